// Round 3
// baseline (1859.623 us; speedup 1.0000x reference)
//
#include <hip/hip_runtime.h>
#include <hip/hip_bf16.h>
#include <math.h>

#define Bq 2
#define Cq 64
#define Hq 192
#define Wq 192
#define HWq (Hq*Wq)            // 36864
#define Nq ((size_t)Bq*Cq*HWq) // 4718592

// ---------------------------------------------------------------------------
// Prep: fold BN into convs, compose the 3 depthwise convs into one 19-tap
// kernel, transpose dsc weights to [k][i][o], fold last BN into 1x1 weights.
// ---------------------------------------------------------------------------
__global__ __launch_bounds__(256) void prep_kernel(
    const float* hc1_w, const float* hc1_b, const float* hc2_w, const float* hc2_b,
    const float* hc3_w, const float* hc3_b,
    const float* vc1_w, const float* vc1_b, const float* vc2_w, const float* vc2_b,
    const float* vc3_w, const float* vc3_b,
    const float* h_off_w, const float* h_off_b, const float* h_bn_g, const float* h_bn_b,
    const float* h_bn_m, const float* h_bn_v, const float* h_dsc_w,
    const float* v_off_w, const float* v_off_b, const float* v_bn_g, const float* v_bn_b,
    const float* v_bn_m, const float* v_bn_v, const float* v_dsc_w,
    const float* last_w, const float* last_g, const float* last_b, const float* last_m,
    const float* last_v,
    float* wEffH, float* bEffH, float* wEffV, float* bEffV,
    float* wtH, float* wtV,
    float* wOffH, float* bOffH, float* wOffV, float* bOffV,
    float* lwT, float* lbO)
{
  int t = threadIdx.x;
  // ---- effective depthwise weights (9 * 7 * 5 -> 19 taps) -----------------
  if (t < 128) {
    int ch = t & 63;
    bool ish = t < 64;
    const float* w1 = (ish ? hc1_w : vc1_w) + ch*9;
    const float* w2 = (ish ? hc2_w : vc2_w) + ch*7;
    const float* w3 = (ish ? hc3_w : vc3_w) + ch*5;
    float t15[15];
    for (int s = 0; s < 15; s++) {
      float a = 0.f;
      for (int j = 0; j < 9; j++) { int k2 = s - j; if (k2 >= 0 && k2 < 7) a += w1[j]*w2[k2]; }
      t15[s] = a;
    }
    float* we = (ish ? wEffH : wEffV) + ch*19;
    for (int s = 0; s < 19; s++) {
      float a = 0.f;
      for (int j = 0; j < 15; j++) { int k3 = s - j; if (k3 >= 0 && k3 < 5) a += t15[j]*w3[k3]; }
      we[s] = a;
    }
    float S2 = 0.f, S3 = 0.f;
    for (int j = 0; j < 7; j++) S2 += w2[j];
    for (int j = 0; j < 5; j++) S3 += w3[j];
    float b1 = (ish ? hc1_b : vc1_b)[ch];
    float b2 = (ish ? hc2_b : vc2_b)[ch];
    float b3 = (ish ? hc3_b : vc3_b)[ch];
    (ish ? bEffH : bEffV)[ch] = b1*S2*S3 + b2*S3 + b3;
  }
  // ---- dsc weight transpose: (o,i,k) -> [k][i][o] -------------------------
  for (int idx = t; idx < 64*64*7; idx += 256) {
    int o = idx / 448; int rem = idx % 448; int i = rem / 7; int k = rem % 7;
    wtH[(k*64 + i)*64 + o] = h_dsc_w[idx];
    wtV[(k*64 + i)*64 + o] = v_dsc_w[idx];
  }
  // ---- offset conv, BN-folded; only needed 7 channels; [tap][i][8pad] -----
  for (int idx = t; idx < 9*64*7; idx += 256) {
    int tap = idx / 448; int rem = idx % 448; int i = rem / 7; int m = rem % 7;
    float invh = h_bn_g[m] / sqrtf(h_bn_v[m] + 1e-5f);
    wOffH[(tap*64 + i)*8 + m] = h_off_w[(m*64 + i)*9 + tap] * invh;
    float invv = v_bn_g[7+m] / sqrtf(v_bn_v[7+m] + 1e-5f);
    wOffV[(tap*64 + i)*8 + m] = v_off_w[((7+m)*64 + i)*9 + tap] * invv;
  }
  if (t < 7) {
    float invh = h_bn_g[t] / sqrtf(h_bn_v[t] + 1e-5f);
    bOffH[t] = h_off_b[t]*invh + h_bn_b[t] - h_bn_m[t]*invh;
    float invv = v_bn_g[7+t] / sqrtf(v_bn_v[7+t] + 1e-5f);
    bOffV[t] = v_off_b[7+t]*invv + v_bn_b[7+t] - v_bn_m[7+t]*invv;
  }
  // ---- last 1x1 conv, BN-folded, transposed [i][o] ------------------------
  for (int idx = t; idx < 4096; idx += 256) {
    int o = idx % 64; int i = idx / 64;
    float inv = last_g[o] / sqrtf(last_v[o] + 1e-3f);
    lwT[i*64 + o] = last_w[o*64 + i] * inv;
  }
  if (t < 64) {
    float inv = last_g[t] / sqrtf(last_v[t] + 1e-3f);
    lbO[t] = last_b[t] - last_m[t]*inv;
  }
}

// ---------------------------------------------------------------------------
// 7x7 conv 64->64, pad 3. Block: 256 thr = 16 o x 16 pixel-groups,
// tile = 4 rows x 64 cols, 16 px per thread. LDS-staged per input channel.
// ---------------------------------------------------------------------------
__global__ __launch_bounds__(256) void conv7x7_kernel(
    const float* __restrict__ x, const float* __restrict__ w, float* __restrict__ out)
{
  __shared__ __align__(16) float sx[10][72];
  __shared__ float sw[16][52];
  int ct = blockIdx.x, rt = blockIdx.y;
  int ob = blockIdx.z & 3, b = blockIdx.z >> 2;
  int r0 = rt*4, c0 = ct*64;
  int t = threadIdx.x;
  int g = t & 15, ol = t >> 4;
  int row_l = g >> 2;
  int cs = (g & 3) * 16;
  int obase = ob*16;
  float acc[16];
#pragma unroll
  for (int p = 0; p < 16; p++) acc[p] = 0.f;
  const float* xb = x + (size_t)b*Cq*HWq;
  for (int i = 0; i < 64; i++) {
    for (int idx = t; idx < 720; idx += 256) {
      int lr = idx / 72, lc = idx % 72;
      int gr = r0 - 3 + lr, gc = c0 - 4 + lc;
      float v = 0.f;
      if (gr >= 0 && gr < Hq && gc >= 0 && gc < Wq) v = xb[(size_t)i*HWq + gr*Wq + gc];
      sx[lr][lc] = v;
    }
    for (int idx = t; idx < 784; idx += 256) {
      int oo = idx / 49, tap = idx % 49;
      sw[oo][tap] = w[((size_t)(obase + oo)*64 + i)*49 + tap];
    }
    __syncthreads();
#pragma unroll
    for (int dy = 0; dy < 7; dy++) {
      float xr[24];
      const float* rowp = &sx[row_l + dy][cs];
#pragma unroll
      for (int q = 0; q < 6; q++) {
        float4 v4 = *reinterpret_cast<const float4*>(rowp + 4*q);
        xr[4*q+0] = v4.x; xr[4*q+1] = v4.y; xr[4*q+2] = v4.z; xr[4*q+3] = v4.w;
      }
#pragma unroll
      for (int dx = 0; dx < 7; dx++) {
        float wv = sw[ol][dy*7 + dx];
#pragma unroll
        for (int p = 0; p < 16; p++) acc[p] += wv * xr[p + dx + 1];
      }
    }
    __syncthreads();
  }
  float* op = out + ((size_t)(b*Cq + obase + ol)*Hq + (r0 + row_l))*Wq + c0 + cs;
#pragma unroll
  for (int p = 0; p < 16; p++) op[p] = acc[p];
}

// ---------------------------------------------------------------------------
// Separable 7x7 avg pool (sum with zero pad, /49)
// ---------------------------------------------------------------------------
__global__ __launch_bounds__(256) void pool_row_kernel(const float* __restrict__ in, float* __restrict__ out)
{
  int idx = blockIdx.x*256 + threadIdx.x;
  int c = idx % Wq;
  int base = idx - c;
  float s = 0.f;
#pragma unroll
  for (int dc = -3; dc <= 3; dc++) {
    int cc = c + dc;
    if (cc >= 0 && cc < Wq) s += in[base + cc];
  }
  out[idx] = s;
}

__global__ __launch_bounds__(256) void pool_col_kernel(const float* __restrict__ in, float* __restrict__ out)
{
  int idx = blockIdx.x*256 + threadIdx.x;
  int c = idx % Wq;
  int r = (idx / Wq) % Hq;
  int plane = idx / HWq;
  float s = 0.f;
#pragma unroll
  for (int dr = -3; dr <= 3; dr++) {
    int rr = r + dr;
    if (rr >= 0 && rr < Hq) s += in[(size_t)plane*HWq + rr*Wq + c];
  }
  out[idx] = s * (1.f/49.f);
}

// ---------------------------------------------------------------------------
// Depthwise conv chain 9->7->5. Fast path only where ALL reads are in-bounds
// AND the composition is valid: cols/rows in [9, W-10]. Borders use the exact
// 3-stage clipped form (sequential zero-padding zeroes INTERMEDIATE
// activations, not just x1).
// ---------------------------------------------------------------------------
__global__ __launch_bounds__(256) void dw_h_kernel(const float* __restrict__ x1, const float* __restrict__ wEff,
                                                   const float* __restrict__ bEff,
                                                   const float* __restrict__ w1p, const float* __restrict__ b1p,
                                                   const float* __restrict__ w2p, const float* __restrict__ b2p,
                                                   const float* __restrict__ w3p, const float* __restrict__ b3p,
                                                   float* __restrict__ out)
{
  int b = blockIdx.z, ch = blockIdx.y;
  int p = blockIdx.x*256 + threadIdx.x;
  int r = p / Wq, c = p % Wq;
  const float* src = x1 + (size_t)(b*Cq + ch)*HWq + r*Wq;
  float s;
  if (c >= 9 && c < Wq-9) {
    const float* w = wEff + ch*19;
    s = bEff[ch];
#pragma unroll
    for (int j = 0; j < 19; j++) s += src[c + j - 9] * w[j];
  } else {
    const float* w1 = w1p + ch*9;
    const float* w2 = w2p + ch*7;
    const float* w3 = w3p + ch*5;
    float b1 = b1p[ch], b2 = b2p[ch];
    s = b3p[ch];
    for (int m = 0; m < 5; m++) {
      int d = c + m - 2;
      if (d < 0 || d >= Wq) continue;
      float s2 = b2;
      for (int k = 0; k < 7; k++) {
        int e = d + k - 3;
        if (e < 0 || e >= Wq) continue;
        float s1 = b1;
        for (int j = 0; j < 9; j++) {
          int cc = e + j - 4;
          if (cc >= 0 && cc < Wq) s1 += src[cc] * w1[j];
        }
        s2 += s1 * w2[k];
      }
      s += s2 * w3[m];
    }
  }
  out[(size_t)(b*Cq + ch)*HWq + p] = s;
}

__global__ __launch_bounds__(256) void dw_v_kernel(const float* __restrict__ x1, const float* __restrict__ wEff,
                                                   const float* __restrict__ bEff,
                                                   const float* __restrict__ w1p, const float* __restrict__ b1p,
                                                   const float* __restrict__ w2p, const float* __restrict__ b2p,
                                                   const float* __restrict__ w3p, const float* __restrict__ b3p,
                                                   float* __restrict__ out)
{
  int b = blockIdx.z, ch = blockIdx.y;
  int p = blockIdx.x*256 + threadIdx.x;
  int r = p / Wq, c = p % Wq;
  const float* src = x1 + (size_t)(b*Cq + ch)*HWq + c;
  float s;
  if (r >= 9 && r < Hq-9) {
    const float* w = wEff + ch*19;
    s = bEff[ch];
#pragma unroll
    for (int j = 0; j < 19; j++) s += src[(r + j - 9)*Wq] * w[j];
  } else {
    const float* w1 = w1p + ch*9;
    const float* w2 = w2p + ch*7;
    const float* w3 = w3p + ch*5;
    float b1 = b1p[ch], b2 = b2p[ch];
    s = b3p[ch];
    for (int m = 0; m < 5; m++) {
      int d = r + m - 2;
      if (d < 0 || d >= Hq) continue;
      float s2 = b2;
      for (int k = 0; k < 7; k++) {
        int e = d + k - 3;
        if (e < 0 || e >= Hq) continue;
        float s1 = b1;
        for (int j = 0; j < 9; j++) {
          int rr = e + j - 4;
          if (rr >= 0 && rr < Hq) s1 += src[rr*Wq] * w1[j];
        }
        s2 += s1 * w2[k];
      }
      s += s2 * w3[m];
    }
  }
  out[(size_t)(b*Cq + ch)*HWq + p] = s;
}

// ---------------------------------------------------------------------------
// Offset conv (3x3, 64->7, BN folded) + tanh + cum_offset
// ---------------------------------------------------------------------------
__global__ __launch_bounds__(256) void off_cum_kernel(const float* __restrict__ feat,
                                                      const float* __restrict__ wOff,
                                                      const float* __restrict__ bOff,
                                                      float* __restrict__ cum)
{
  int b = blockIdx.y;
  int p = blockIdx.x*256 + threadIdx.x;
  int r = p / Wq, c = p % Wq;
  float tv[7];
#pragma unroll
  for (int m = 0; m < 7; m++) tv[m] = bOff[m];
  const float* fb = feat + (size_t)b*Cq*HWq;
  for (int tap = 0; tap < 9; tap++) {
    int dy = tap/3 - 1, dx = tap%3 - 1;
    int rr = r + dy, cc = c + dx;
    if (rr < 0 || rr >= Hq || cc < 0 || cc >= Wq) continue;
    const float* fp = fb + rr*Wq + cc;
    const float* wp = wOff + tap*512;
    for (int i = 0; i < 64; i++) {
      float fv = fp[(size_t)i*HWq];
#pragma unroll
      for (int m = 0; m < 7; m++) tv[m] += fv * wp[i*8 + m];
    }
  }
#pragma unroll
  for (int m = 0; m < 7; m++) tv[m] = tanhf(tv[m]);
  float c0 = tv[0], c1 = tv[1] + tv[2], c2 = tv[2], c3 = 0.f;
  float c4 = tv[4], c5 = tv[4] + tv[5], c6 = tv[6];
  size_t bb = (size_t)b*7*HWq + p;
  cum[bb + 0*HWq] = c0; cum[bb + 1*HWq] = c1; cum[bb + 2*HWq] = c2;
  cum[bb + 3*HWq] = c3; cum[bb + 4*HWq] = c4; cum[bb + 5*HWq] = c5;
  cum[bb + 6*HWq] = c6;
}

// ---------------------------------------------------------------------------
// Deformable sample + einsum, morph=0 (h): x integer, y = r + cum
// ---------------------------------------------------------------------------
__global__ __launch_bounds__(256) void einsum_h_kernel(const float* __restrict__ feat,
                                                       const float* __restrict__ cum,
                                                       const float* __restrict__ wt,
                                                       const float* __restrict__ dsc_b,
                                                       float* __restrict__ out)
{
  int b = blockIdx.y;
  int p = blockIdx.x*256 + threadIdx.x;
  int r = p / Wq, c = p % Wq;
  float acc[64];
#pragma unroll
  for (int o = 0; o < 64; o++) acc[o] = dsc_b[o];
  const float* fb = feat + (size_t)b*Cq*HWq;
  for (int k = 0; k < 7; k++) {
    int xi = c + k - 3;
    if (xi < 0 || xi > Wq-1) continue;
    float y = (float)r + cum[((size_t)(b*7 + k))*HWq + p];
    float y0 = floorf(y);
    int y0q = (int)y0;
    int y0i = min(max(y0q, 0), Hq-1);
    int y1i = min(max(y0q + 1, 0), Hq-1);
    float y0f = fminf(fmaxf(y0, 0.f), (float)Hq);
    float y1f = fminf(fmaxf(y0 + 1.f, 0.f), (float)Hq);
    float w0 = y1f - y, w1 = y - y0f;
    const float* f0 = fb + y0i*Wq + xi;
    const float* f1 = fb + y1i*Wq + xi;
    const float* wk = wt + k*4096;
    for (int i = 0; i < 64; i++) {
      float sv = w0*f0[(size_t)i*HWq] + w1*f1[(size_t)i*HWq];
      const float* wr = wk + i*64;
#pragma unroll
      for (int o = 0; o < 64; o++) acc[o] += sv * wr[o];
    }
  }
  float* dst = out + (size_t)b*Cq*HWq + p;
#pragma unroll
  for (int o = 0; o < 64; o++) dst[(size_t)o*HWq] = acc[o];
}

// morph=1 (v): y integer, x = c + cum
__global__ __launch_bounds__(256) void einsum_v_kernel(const float* __restrict__ feat,
                                                       const float* __restrict__ cum,
                                                       const float* __restrict__ wt,
                                                       const float* __restrict__ dsc_b,
                                                       float* __restrict__ out)
{
  int b = blockIdx.y;
  int p = blockIdx.x*256 + threadIdx.x;
  int r = p / Wq, c = p % Wq;
  float acc[64];
#pragma unroll
  for (int o = 0; o < 64; o++) acc[o] = dsc_b[o];
  const float* fb = feat + (size_t)b*Cq*HWq;
  for (int k = 0; k < 7; k++) {
    int yi = r + k - 3;
    if (yi < 0 || yi > Hq-1) continue;
    float xf = (float)c + cum[((size_t)(b*7 + k))*HWq + p];
    float x0 = floorf(xf);
    int x0q = (int)x0;
    int x0i = min(max(x0q, 0), Wq-1);
    int x1i = min(max(x0q + 1, 0), Wq-1);
    float x0f = fminf(fmaxf(x0, 0.f), (float)Wq);
    float x1f = fminf(fmaxf(x0 + 1.f, 0.f), (float)Wq);
    float w0 = x1f - xf, w1 = xf - x0f;
    const float* f0 = fb + yi*Wq;
    const float* wk = wt + k*4096;
    for (int i = 0; i < 64; i++) {
      const float* fi = f0 + (size_t)i*HWq;
      float sv = w0*fi[x0i] + w1*fi[x1i];
      const float* wr = wk + i*64;
#pragma unroll
      for (int o = 0; o < 64; o++) acc[o] += sv * wr[o];
    }
  }
  float* dst = out + (size_t)b*Cq*HWq + p;
#pragma unroll
  for (int o = 0; o < 64; o++) dst[(size_t)o*HWq] = acc[o];
}

// ---------------------------------------------------------------------------
// GroupNorm stats: one block per (buf, b, ch) plane, deterministic
// ---------------------------------------------------------------------------
__global__ __launch_bounds__(256) void gnstats_kernel(const float* __restrict__ h_ds,
                                                      const float* __restrict__ v_ds,
                                                      float* __restrict__ stats)
{
  int plane = blockIdx.x;           // 0..255
  int buf = plane >> 7;
  int rem = plane & 127;
  const float* src = (buf ? v_ds : h_ds) + (size_t)rem*HWq;
  float s = 0.f, s2 = 0.f;
  for (int i = threadIdx.x; i < HWq; i += 256) {
    float v = src[i];
    s += v; s2 += v*v;
  }
  __shared__ float red[2][4];
  for (int off = 32; off; off >>= 1) {
    s  += __shfl_down(s, off);
    s2 += __shfl_down(s2, off);
  }
  if ((threadIdx.x & 63) == 0) { red[0][threadIdx.x >> 6] = s; red[1][threadIdx.x >> 6] = s2; }
  __syncthreads();
  if (threadIdx.x == 0) {
    s  = red[0][0] + red[0][1] + red[0][2] + red[0][3];
    s2 = red[1][0] + red[1][1] + red[1][2] + red[1][3];
    stats[plane*2 + 0] = s;
    stats[plane*2 + 1] = s2;
  }
}

__global__ __launch_bounds__(256) void gnfinal_kernel(const float* __restrict__ stats,
                                                      const float* __restrict__ h_gn_g, const float* __restrict__ h_gn_b,
                                                      const float* __restrict__ v_gn_g, const float* __restrict__ v_gn_b,
                                                      float* __restrict__ gnAB)
{
  int t = threadIdx.x;              // 256 = 2 buf * 2 b * 64 ch
  int buf = t >> 7, ch = t & 63;
  int base = t & ~3;                // group base plane
  float sum = 0.f, ss = 0.f;
#pragma unroll
  for (int q = 0; q < 4; q++) { sum += stats[(base+q)*2]; ss += stats[(base+q)*2 + 1]; }
  const float n = 4.f * HWq;
  float mean = sum / n;
  float var = ss / n - mean*mean;
  float gg = (buf ? v_gn_g : h_gn_g)[ch];
  float bb = (buf ? v_gn_b : h_gn_b)[ch];
  float A = gg / sqrtf(var + 1e-5f);
  gnAB[t*2 + 0] = A;
  gnAB[t*2 + 1] = bb - mean*A;
}

// ---------------------------------------------------------------------------
// comb = relu(GN(h)) + relu(GN(v)) + x1
// ---------------------------------------------------------------------------
__global__ __launch_bounds__(256) void combine_kernel(const float* __restrict__ h_ds,
                                                      const float* __restrict__ v_ds,
                                                      const float* __restrict__ x1,
                                                      const float* __restrict__ gnAB,
                                                      float* __restrict__ comb)
{
  size_t idx = (size_t)blockIdx.x*256 + threadIdx.x;
  int plane = (int)(idx / HWq);     // b*64+ch, 0..127
  int ih = plane*2;                 // buf=0
  int iv = (128 + plane)*2;         // buf=1
  float hv = h_ds[idx]*gnAB[ih] + gnAB[ih+1]; hv = fmaxf(hv, 0.f);
  float vv = v_ds[idx]*gnAB[iv] + gnAB[iv+1]; vv = fmaxf(vv, 0.f);
  comb[idx] = hv + vv + x1[idx];
}

// ---------------------------------------------------------------------------
// final: 1x1 conv (BN folded) + SiLU
// ---------------------------------------------------------------------------
__global__ __launch_bounds__(256) void final_kernel(const float* __restrict__ comb,
                                                    const float* __restrict__ lwT,
                                                    const float* __restrict__ lbO,
                                                    float* __restrict__ out)
{
  int b = blockIdx.y;
  int p = blockIdx.x*256 + threadIdx.x;
  const float* cb = comb + (size_t)b*Cq*HWq + p;
  float acc[64];
#pragma unroll
  for (int o = 0; o < 64; o++) acc[o] = 0.f;
  for (int i = 0; i < 64; i++) {
    float cv = cb[(size_t)i*HWq];
    const float* wr = lwT + i*64;
#pragma unroll
    for (int o = 0; o < 64; o++) acc[o] += cv * wr[o];
  }
  float* dst = out + (size_t)b*Cq*HWq + p;
#pragma unroll
  for (int o = 0; o < 64; o++) {
    float yv = acc[o] + lbO[o];
    dst[(size_t)o*HWq] = yv / (1.f + expf(-yv));
  }
}

// ---------------------------------------------------------------------------
extern "C" void kernel_launch(void* const* d_in, const int* in_sizes, int n_in,
                              void* d_out, int out_size, void* d_ws, size_t ws_size,
                              hipStream_t stream)
{
  const float* x       = (const float*)d_in[0];
  const float* w_first = (const float*)d_in[1];
  float* ws = (float*)d_ws;

  float* bufA = ws;            // conv7 out -> hfeat -> comb
  float* bufB = ws + Nq;       // rowsum -> vfeat
  float* x1   = ws + 2*Nq;
  float* h_ds = ws + 3*Nq;
  float* v_ds = ws + 4*Nq;
  size_t off = 5*Nq;
  float* hcum  = ws + off; off += (size_t)Bq*7*HWq;
  float* vcum  = ws + off; off += (size_t)Bq*7*HWq;
  float* wEffH = ws + off; off += 64*19;
  float* bEffH = ws + off; off += 64;
  float* wEffV = ws + off; off += 64*19;
  float* bEffV = ws + off; off += 64;
  float* wtH   = ws + off; off += 64*64*7;
  float* wtV   = ws + off; off += 64*64*7;
  float* wOffH = ws + off; off += 9*64*8;
  float* bOffH = ws + off; off += 8;
  float* wOffV = ws + off; off += 9*64*8;
  float* bOffV = ws + off; off += 8;
  float* lwT   = ws + off; off += 64*64;
  float* lbO   = ws + off; off += 64;
  float* stats = ws + off; off += 512;
  float* gnAB  = ws + off; off += 512;

  prep_kernel<<<dim3(1), dim3(256), 0, stream>>>(
      (const float*)d_in[2],  (const float*)d_in[3],  (const float*)d_in[4],  (const float*)d_in[5],
      (const float*)d_in[6],  (const float*)d_in[7],
      (const float*)d_in[8],  (const float*)d_in[9],  (const float*)d_in[10], (const float*)d_in[11],
      (const float*)d_in[12], (const float*)d_in[13],
      (const float*)d_in[14], (const float*)d_in[15], (const float*)d_in[16], (const float*)d_in[17],
      (const float*)d_in[18], (const float*)d_in[19], (const float*)d_in[20],
      (const float*)d_in[24], (const float*)d_in[25], (const float*)d_in[26], (const float*)d_in[27],
      (const float*)d_in[28], (const float*)d_in[29], (const float*)d_in[30],
      (const float*)d_in[34], (const float*)d_in[35], (const float*)d_in[36], (const float*)d_in[37],
      (const float*)d_in[38],
      wEffH, bEffH, wEffV, bEffV, wtH, wtV, wOffH, bOffH, wOffV, bOffV, lwT, lbO);

  conv7x7_kernel<<<dim3(3, 48, 8), dim3(256), 0, stream>>>(x, w_first, bufA);
  pool_row_kernel<<<dim3(18432), dim3(256), 0, stream>>>(bufA, bufB);
  pool_col_kernel<<<dim3(18432), dim3(256), 0, stream>>>(bufB, x1);

  dw_h_kernel<<<dim3(144, 64, 2), dim3(256), 0, stream>>>(x1, wEffH, bEffH,
      (const float*)d_in[2], (const float*)d_in[3], (const float*)d_in[4], (const float*)d_in[5],
      (const float*)d_in[6], (const float*)d_in[7], bufA);
  dw_v_kernel<<<dim3(144, 64, 2), dim3(256), 0, stream>>>(x1, wEffV, bEffV,
      (const float*)d_in[8], (const float*)d_in[9], (const float*)d_in[10], (const float*)d_in[11],
      (const float*)d_in[12], (const float*)d_in[13], bufB);

  off_cum_kernel<<<dim3(144, 2), dim3(256), 0, stream>>>(bufA, wOffH, bOffH, hcum);
  off_cum_kernel<<<dim3(144, 2), dim3(256), 0, stream>>>(bufB, wOffV, bOffV, vcum);

  einsum_h_kernel<<<dim3(144, 2), dim3(256), 0, stream>>>(bufA, hcum, wtH, (const float*)d_in[21], h_ds);
  einsum_v_kernel<<<dim3(144, 2), dim3(256), 0, stream>>>(bufB, vcum, wtV, (const float*)d_in[31], v_ds);

  gnstats_kernel<<<dim3(256), dim3(256), 0, stream>>>(h_ds, v_ds, stats);
  gnfinal_kernel<<<dim3(1), dim3(256), 0, stream>>>(stats,
      (const float*)d_in[22], (const float*)d_in[23],
      (const float*)d_in[32], (const float*)d_in[33], gnAB);

  combine_kernel<<<dim3(18432), dim3(256), 0, stream>>>(h_ds, v_ds, x1, gnAB, bufA);
  final_kernel<<<dim3(144, 2), dim3(256), 0, stream>>>(bufA, lwT, lbO, (float*)d_out);
}

// Round 5
// 1036.029 us; speedup vs baseline: 1.7950x; 1.7950x over previous
//
#include <hip/hip_runtime.h>
#include <hip/hip_bf16.h>
#include <hip/hip_fp16.h>
#include <math.h>

#define Bq 2
#define Cq 64
#define Hq 192
#define Wq 192
#define HWq (Hq*Wq)            // 36864
#define Nq ((size_t)Bq*Cq*HWq) // 4718592

typedef __attribute__((ext_vector_type(8))) _Float16 f16x8;
typedef __attribute__((ext_vector_type(4))) float f32x4;

__device__ inline unsigned short h2us(__half h) {
  union { __half h; unsigned short u; } v; v.h = h; return v.u;
}

// ---------------------------------------------------------------------------
// Small prep (1 block): fold BN, compose depthwise chain, offset conv fold,
// last 1x1 fold.
// ---------------------------------------------------------------------------
__global__ __launch_bounds__(256) void prep_small_kernel(
    const float* hc1_w, const float* hc1_b, const float* hc2_w, const float* hc2_b,
    const float* hc3_w, const float* hc3_b,
    const float* vc1_w, const float* vc1_b, const float* vc2_w, const float* vc2_b,
    const float* vc3_w, const float* vc3_b,
    const float* h_off_w, const float* h_off_b, const float* h_bn_g, const float* h_bn_b,
    const float* h_bn_m, const float* h_bn_v,
    const float* v_off_w, const float* v_off_b, const float* v_bn_g, const float* v_bn_b,
    const float* v_bn_m, const float* v_bn_v,
    const float* last_w, const float* last_g, const float* last_b, const float* last_m,
    const float* last_v,
    float* wEffH, float* bEffH, float* wEffV, float* bEffV,
    float* wOffH, float* bOffH, float* wOffV, float* bOffV,
    float* lwT, float* lbO)
{
  int t = threadIdx.x;
  if (t < 128) {
    int ch = t & 63;
    bool ish = t < 64;
    const float* w1 = (ish ? hc1_w : vc1_w) + ch*9;
    const float* w2 = (ish ? hc2_w : vc2_w) + ch*7;
    const float* w3 = (ish ? hc3_w : vc3_w) + ch*5;
    float t15[15];
    for (int s = 0; s < 15; s++) {
      float a = 0.f;
      for (int j = 0; j < 9; j++) { int k2 = s - j; if (k2 >= 0 && k2 < 7) a += w1[j]*w2[k2]; }
      t15[s] = a;
    }
    float* we = (ish ? wEffH : wEffV) + ch*19;
    for (int s = 0; s < 19; s++) {
      float a = 0.f;
      for (int j = 0; j < 15; j++) { int k3 = s - j; if (k3 >= 0 && k3 < 5) a += t15[j]*w3[k3]; }
      we[s] = a;
    }
    float S2 = 0.f, S3 = 0.f;
    for (int j = 0; j < 7; j++) S2 += w2[j];
    for (int j = 0; j < 5; j++) S3 += w3[j];
    float b1 = (ish ? hc1_b : vc1_b)[ch];
    float b2 = (ish ? hc2_b : vc2_b)[ch];
    float b3 = (ish ? hc3_b : vc3_b)[ch];
    (ish ? bEffH : bEffV)[ch] = b1*S2*S3 + b2*S3 + b3;
  }
  for (int idx = t; idx < 9*64*7; idx += 256) {
    int tap = idx / 448; int rem = idx % 448; int i = rem / 7; int m = rem % 7;
    float invh = h_bn_g[m] / sqrtf(h_bn_v[m] + 1e-5f);
    wOffH[(tap*64 + i)*8 + m] = h_off_w[(m*64 + i)*9 + tap] * invh;
    float invv = v_bn_g[7+m] / sqrtf(v_bn_v[7+m] + 1e-5f);
    wOffV[(tap*64 + i)*8 + m] = v_off_w[((7+m)*64 + i)*9 + tap] * invv;
  }
  if (t < 7) {
    float invh = h_bn_g[t] / sqrtf(h_bn_v[t] + 1e-5f);
    bOffH[t] = h_off_b[t]*invh + h_bn_b[t] - h_bn_m[t]*invh;
    float invv = v_bn_g[7+t] / sqrtf(v_bn_v[7+t] + 1e-5f);
    bOffV[t] = v_off_b[7+t]*invv + v_bn_b[7+t] - v_bn_m[7+t]*invv;
  }
  for (int idx = t; idx < 4096; idx += 256) {
    int o = idx % 64; int i = idx / 64;
    float inv = last_g[o] / sqrtf(last_v[o] + 1e-3f);
    lwT[i*64 + o] = last_w[o*64 + i] * inv;
  }
  if (t < 64) {
    float inv = last_g[t] / sqrtf(last_v[t] + 1e-3f);
    lbO[t] = last_b[t] - last_m[t]*inv;
  }
}

// ---------------------------------------------------------------------------
// Big prep (many blocks): dsc weight transpose + w_first f16 hi/lo pack.
// wpack layout: [h(2)][tap(49)][hl(2)][oc(64)][ch(32)] f16.
// ---------------------------------------------------------------------------
__global__ __launch_bounds__(256) void prep_big_kernel(
    const float* __restrict__ w_first,
    const float* __restrict__ h_dsc_w, const float* __restrict__ v_dsc_w,
    float* __restrict__ wtH, float* __restrict__ wtV,
    unsigned short* __restrict__ wpack)
{
  int tid = blockIdx.x*256 + threadIdx.x;
  int nthr = gridDim.x*256;
  for (int idx = tid; idx < 64*64*7; idx += nthr) {
    int o = idx / 448; int rem = idx % 448; int i = rem / 7; int k = rem % 7;
    wtH[(k*64 + i)*64 + o] = h_dsc_w[idx];
    wtV[(k*64 + i)*64 + o] = v_dsc_w[idx];
  }
  for (int e = tid; e < 2*49*2*64*32; e += nthr) {
    int ch  = e & 31;
    int oc  = (e >> 5) & 63;
    int hl  = (e >> 11) & 1;
    int rest = e >> 12;
    int tap = rest % 49;
    int h   = rest / 49;
    float wv = w_first[((size_t)oc*64 + h*32 + ch)*49 + tap];
    __half hh = __float2half(wv);
    unsigned short us;
    if (!hl) us = h2us(hh);
    else { float rr = wv - __half2float(hh); us = h2us(__float2half(rr)); }
    wpack[e] = us;
  }
}

// ---------------------------------------------------------------------------
// x (NCHW f32) -> xpack: per pixel 16 granules of 8 f16:
// [h(2)][hl(2)][g8(4)] x 8 ch. One block per (row, batch).
// ---------------------------------------------------------------------------
__global__ __launch_bounds__(192) void tof16_pack_kernel(const float* __restrict__ x,
                                                         unsigned short* __restrict__ xpack)
{
  __shared__ unsigned int s[192*64];   // [col][ch] (lo16=hi-part, hi16=lo-part)
  int r = blockIdx.x, b = blockIdx.y;
  int t = threadIdx.x;                 // column
  for (int ch = 0; ch < 64; ch++) {
    float v = x[((size_t)(b*64+ch)*Hq + r)*Wq + t];
    __half hh = __float2half(v);
    float rr = v - __half2float(hh);
    __half hl = __float2half(rr);
    unsigned int pk = (unsigned int)h2us(hh) | ((unsigned int)h2us(hl) << 16);
    s[t*64 + (ch ^ (t & 31))] = pk;
  }
  __syncthreads();
  unsigned short* dst = xpack + ((size_t)b*Hq + r)*Wq*128;
  for (int i = 0; i < 16; i++) {
    int gidx = i*192 + t;              // 3072 granules per (row,b)
    int c = gidx >> 4, sub = gidx & 15;
    int h = sub >> 3, hl = (sub >> 2) & 1, g8 = sub & 3;
    unsigned short tmp[8];
#pragma unroll
    for (int j = 0; j < 8; j++) {
      int ch = h*32 + g8*8 + j;
      unsigned int u = s[c*64 + (ch ^ (c & 31))];
      tmp[j] = hl ? (unsigned short)(u >> 16) : (unsigned short)(u & 0xffff);
    }
    uint4 v;
    v.x = (unsigned int)tmp[0] | ((unsigned int)tmp[1] << 16);
    v.y = (unsigned int)tmp[2] | ((unsigned int)tmp[3] << 16);
    v.z = (unsigned int)tmp[4] | ((unsigned int)tmp[5] << 16);
    v.w = (unsigned int)tmp[6] | ((unsigned int)tmp[7] << 16);
    *(uint4*)(dst + (size_t)gidx*8) = v;
  }
}

// ---------------------------------------------------------------------------
// 7x7 conv 64->64 pad 3, MFMA implicit GEMM, f16 hi/lo 3-pass.
// Block: 192 thr = 3 waves; wave = 1 output row x 48 cols; 64 oc.
// A staged in LDS (hi+lo, granule-XOR swizzle); B read direct from global
// (1KB coalesced tiles, L2-resident).
// ---------------------------------------------------------------------------
__global__ __launch_bounds__(192) void conv7_mfma_kernel(
    const unsigned short* __restrict__ xpack,
    const unsigned short* __restrict__ wpack,
    float* __restrict__ out)
{
  __shared__ __align__(16) unsigned short sA[9*54*64];  // 62208 B
  int ct = blockIdx.x;          // 0..3
  int rt = blockIdx.y;          // 0..63
  int b  = blockIdx.z;
  int r0 = rt*3, c0 = ct*48;
  int t = threadIdx.x;
  int w = t >> 6;               // wave -> output row offset
  int l = t & 63;
  int l15 = l & 15, lg = l >> 4;

  f32x4 acc[3][4];
#pragma unroll
  for (int i = 0; i < 3; i++)
#pragma unroll
    for (int j = 0; j < 4; j++) acc[i][j] = (f32x4){0.f,0.f,0.f,0.f};

  for (int h = 0; h < 2; h++) {
    __syncthreads();            // readers of prev half done
    for (int idx = t; idx < 9*54*8; idx += 192) {
      int g = idx & 7, pix = idx >> 3;
      int row = pix / 54, col = pix % 54;
      int gr = r0 - 3 + row, gc = c0 - 3 + col;
      uint4 v = {0u,0u,0u,0u};
      if (gr >= 0 && gr < Hq && gc >= 0 && gc < Wq)
        v = *(const uint4*)(xpack + (((size_t)b*Hq + gr)*Wq + gc)*128 + (h*8 + g)*8);
      ((uint4*)sA)[(row*54 + col)*8 + (g ^ (col & 7))] = v;
    }
    __syncthreads();
    const unsigned short* wb = wpack + (size_t)h*49*4096;
    for (int tap = 0; tap < 49; tap++) {
      int dy = tap / 7, dx = tap % 7;
      f16x8 bh[4], bl[4];
#pragma unroll
      for (int tb = 0; tb < 4; tb++) {
        bh[tb] = *(const f16x8*)(wb + (size_t)tap*4096 + (tb*16 + l15)*32 + lg*8);
        bl[tb] = *(const f16x8*)(wb + (size_t)tap*4096 + 2048 + (tb*16 + l15)*32 + lg*8);
      }
      int arow = w + dy;
      f16x8 ah[3], al[3];
#pragma unroll
      for (int ta = 0; ta < 3; ta++) {
        int col = ta*16 + l15 + dx;
        const uint4* base = (const uint4*)sA + (arow*54 + col)*8;
        ah[ta] = *(const f16x8*)(base + (lg ^ (col & 7)));
        al[ta] = *(const f16x8*)(base + ((lg + 4) ^ (col & 7)));
      }
#pragma unroll
      for (int ta = 0; ta < 3; ta++)
#pragma unroll
        for (int tb = 0; tb < 4; tb++) {
          acc[ta][tb] = __builtin_amdgcn_mfma_f32_16x16x32_f16(ah[ta], bh[tb], acc[ta][tb], 0, 0, 0);
          acc[ta][tb] = __builtin_amdgcn_mfma_f32_16x16x32_f16(ah[ta], bl[tb], acc[ta][tb], 0, 0, 0);
          acc[ta][tb] = __builtin_amdgcn_mfma_f32_16x16x32_f16(al[ta], bh[tb], acc[ta][tb], 0, 0, 0);
        }
    }
  }
#pragma unroll
  for (int tb = 0; tb < 4; tb++) {
    int oc = tb*16 + l15;
    float* dst = out + ((size_t)(b*64 + oc)*Hq + (r0 + w))*Wq + c0;
#pragma unroll
    for (int ta = 0; ta < 3; ta++) {
      f32x4 v = acc[ta][tb];
      *(float4*)(dst + ta*16 + lg*4) = make_float4(v[0], v[1], v[2], v[3]);
    }
  }
}

// ---------------------------------------------------------------------------
// Separable 7x7 avg pool (sum with zero pad, /49)
// ---------------------------------------------------------------------------
__global__ __launch_bounds__(256) void pool_row_kernel(const float* __restrict__ in, float* __restrict__ out)
{
  int idx = blockIdx.x*256 + threadIdx.x;
  int c = idx % Wq;
  int base = idx - c;
  float s = 0.f;
#pragma unroll
  for (int dc = -3; dc <= 3; dc++) {
    int cc = c + dc;
    if (cc >= 0 && cc < Wq) s += in[base + cc];
  }
  out[idx] = s;
}

__global__ __launch_bounds__(256) void pool_col_kernel(const float* __restrict__ in, float* __restrict__ out)
{
  int idx = blockIdx.x*256 + threadIdx.x;
  int c = idx % Wq;
  int r = (idx / Wq) % Hq;
  int plane = idx / HWq;
  float s = 0.f;
#pragma unroll
  for (int dr = -3; dr <= 3; dr++) {
    int rr = r + dr;
    if (rr >= 0 && rr < Hq) s += in[(size_t)plane*HWq + rr*Wq + c];
  }
  out[idx] = s * (1.f/49.f);
}

// ---------------------------------------------------------------------------
// Depthwise conv chain 9->7->5. Fast path cols/rows in [9, W-10]; borders use
// exact 3-stage clipped form.
// ---------------------------------------------------------------------------
__global__ __launch_bounds__(256) void dw_h_kernel(const float* __restrict__ x1, const float* __restrict__ wEff,
                                                   const float* __restrict__ bEff,
                                                   const float* __restrict__ w1p, const float* __restrict__ b1p,
                                                   const float* __restrict__ w2p, const float* __restrict__ b2p,
                                                   const float* __restrict__ w3p, const float* __restrict__ b3p,
                                                   float* __restrict__ out)
{
  int b = blockIdx.z, ch = blockIdx.y;
  int p = blockIdx.x*256 + threadIdx.x;
  int r = p / Wq, c = p % Wq;
  const float* src = x1 + (size_t)(b*Cq + ch)*HWq + r*Wq;
  float s;
  if (c >= 9 && c < Wq-9) {
    const float* w = wEff + ch*19;
    s = bEff[ch];
#pragma unroll
    for (int j = 0; j < 19; j++) s += src[c + j - 9] * w[j];
  } else {
    const float* w1 = w1p + ch*9;
    const float* w2 = w2p + ch*7;
    const float* w3 = w3p + ch*5;
    float b1 = b1p[ch], b2 = b2p[ch];
    s = b3p[ch];
    for (int m = 0; m < 5; m++) {
      int d = c + m - 2;
      if (d < 0 || d >= Wq) continue;
      float s2 = b2;
      for (int k = 0; k < 7; k++) {
        int e = d + k - 3;
        if (e < 0 || e >= Wq) continue;
        float s1 = b1;
        for (int j = 0; j < 9; j++) {
          int cc = e + j - 4;
          if (cc >= 0 && cc < Wq) s1 += src[cc] * w1[j];
        }
        s2 += s1 * w2[k];
      }
      s += s2 * w3[m];
    }
  }
  out[(size_t)(b*Cq + ch)*HWq + p] = s;
}

__global__ __launch_bounds__(256) void dw_v_kernel(const float* __restrict__ x1, const float* __restrict__ wEff,
                                                   const float* __restrict__ bEff,
                                                   const float* __restrict__ w1p, const float* __restrict__ b1p,
                                                   const float* __restrict__ w2p, const float* __restrict__ b2p,
                                                   const float* __restrict__ w3p, const float* __restrict__ b3p,
                                                   float* __restrict__ out)
{
  int b = blockIdx.z, ch = blockIdx.y;
  int p = blockIdx.x*256 + threadIdx.x;
  int r = p / Wq, c = p % Wq;
  const float* src = x1 + (size_t)(b*Cq + ch)*HWq + c;
  float s;
  if (r >= 9 && r < Hq-9) {
    const float* w = wEff + ch*19;
    s = bEff[ch];
#pragma unroll
    for (int j = 0; j < 19; j++) s += src[(r + j - 9)*Wq] * w[j];
  } else {
    const float* w1 = w1p + ch*9;
    const float* w2 = w2p + ch*7;
    const float* w3 = w3p + ch*5;
    float b1 = b1p[ch], b2 = b2p[ch];
    s = b3p[ch];
    for (int m = 0; m < 5; m++) {
      int d = r + m - 2;
      if (d < 0 || d >= Hq) continue;
      float s2 = b2;
      for (int k = 0; k < 7; k++) {
        int e = d + k - 3;
        if (e < 0 || e >= Hq) continue;
        float s1 = b1;
        for (int j = 0; j < 9; j++) {
          int rr = e + j - 4;
          if (rr >= 0 && rr < Hq) s1 += src[rr*Wq] * w1[j];
        }
        s2 += s1 * w2[k];
      }
      s += s2 * w3[m];
    }
  }
  out[(size_t)(b*Cq + ch)*HWq + p] = s;
}

// ---------------------------------------------------------------------------
// Offset conv (3x3, 64->7, BN folded) + tanh + cum_offset
// ---------------------------------------------------------------------------
__global__ __launch_bounds__(256) void off_cum_kernel(const float* __restrict__ feat,
                                                      const float* __restrict__ wOff,
                                                      const float* __restrict__ bOff,
                                                      float* __restrict__ cum)
{
  int b = blockIdx.y;
  int p = blockIdx.x*256 + threadIdx.x;
  int r = p / Wq, c = p % Wq;
  float tv[7];
#pragma unroll
  for (int m = 0; m < 7; m++) tv[m] = bOff[m];
  const float* fb = feat + (size_t)b*Cq*HWq;
  for (int tap = 0; tap < 9; tap++) {
    int dy = tap/3 - 1, dx = tap%3 - 1;
    int rr = r + dy, cc = c + dx;
    if (rr < 0 || rr >= Hq || cc < 0 || cc >= Wq) continue;
    const float* fp = fb + rr*Wq + cc;
    const float* wp = wOff + tap*512;
    for (int i = 0; i < 64; i++) {
      float fv = fp[(size_t)i*HWq];
#pragma unroll
      for (int m = 0; m < 7; m++) tv[m] += fv * wp[i*8 + m];
    }
  }
#pragma unroll
  for (int m = 0; m < 7; m++) tv[m] = tanhf(tv[m]);
  float c0 = tv[0], c1 = tv[1] + tv[2], c2 = tv[2], c3 = 0.f;
  float c4 = tv[4], c5 = tv[4] + tv[5], c6 = tv[6];
  size_t bb = (size_t)b*7*HWq + p;
  cum[bb + 0*HWq] = c0; cum[bb + 1*HWq] = c1; cum[bb + 2*HWq] = c2;
  cum[bb + 3*HWq] = c3; cum[bb + 4*HWq] = c4; cum[bb + 5*HWq] = c5;
  cum[bb + 6*HWq] = c6;
}

// ---------------------------------------------------------------------------
// Deformable sample + einsum, morph=0 (h)
// ---------------------------------------------------------------------------
__global__ __launch_bounds__(256) void einsum_h_kernel(const float* __restrict__ feat,
                                                       const float* __restrict__ cum,
                                                       const float* __restrict__ wt,
                                                       const float* __restrict__ dsc_b,
                                                       float* __restrict__ out)
{
  int b = blockIdx.y;
  int p = blockIdx.x*256 + threadIdx.x;
  int r = p / Wq, c = p % Wq;
  float acc[64];
#pragma unroll
  for (int o = 0; o < 64; o++) acc[o] = dsc_b[o];
  const float* fb = feat + (size_t)b*Cq*HWq;
  for (int k = 0; k < 7; k++) {
    int xi = c + k - 3;
    if (xi < 0 || xi > Wq-1) continue;
    float y = (float)r + cum[((size_t)(b*7 + k))*HWq + p];
    float y0 = floorf(y);
    int y0q = (int)y0;
    int y0i = min(max(y0q, 0), Hq-1);
    int y1i = min(max(y0q + 1, 0), Hq-1);
    float y0f = fminf(fmaxf(y0, 0.f), (float)Hq);
    float y1f = fminf(fmaxf(y0 + 1.f, 0.f), (float)Hq);
    float w0 = y1f - y, w1 = y - y0f;
    const float* f0 = fb + y0i*Wq + xi;
    const float* f1 = fb + y1i*Wq + xi;
    const float* wk = wt + k*4096;
    for (int i = 0; i < 64; i++) {
      float sv = w0*f0[(size_t)i*HWq] + w1*f1[(size_t)i*HWq];
      const float* wr = wk + i*64;
#pragma unroll
      for (int o = 0; o < 64; o++) acc[o] += sv * wr[o];
    }
  }
  float* dst = out + (size_t)b*Cq*HWq + p;
#pragma unroll
  for (int o = 0; o < 64; o++) dst[(size_t)o*HWq] = acc[o];
}

// morph=1 (v)
__global__ __launch_bounds__(256) void einsum_v_kernel(const float* __restrict__ feat,
                                                       const float* __restrict__ cum,
                                                       const float* __restrict__ wt,
                                                       const float* __restrict__ dsc_b,
                                                       float* __restrict__ out)
{
  int b = blockIdx.y;
  int p = blockIdx.x*256 + threadIdx.x;
  int r = p / Wq, c = p % Wq;
  float acc[64];
#pragma unroll
  for (int o = 0; o < 64; o++) acc[o] = dsc_b[o];
  const float* fb = feat + (size_t)b*Cq*HWq;
  for (int k = 0; k < 7; k++) {
    int yi = r + k - 3;
    if (yi < 0 || yi > Hq-1) continue;
    float xf = (float)c + cum[((size_t)(b*7 + k))*HWq + p];
    float x0 = floorf(xf);
    int x0q = (int)x0;
    int x0i = min(max(x0q, 0), Wq-1);
    int x1i = min(max(x0q + 1, 0), Wq-1);
    float x0f = fminf(fmaxf(x0, 0.f), (float)Wq);
    float x1f = fminf(fmaxf(x0 + 1.f, 0.f), (float)Wq);
    float w0 = x1f - xf, w1 = xf - x0f;
    const float* f0 = fb + yi*Wq;
    const float* wk = wt + k*4096;
    for (int i = 0; i < 64; i++) {
      const float* fi = f0 + (size_t)i*HWq;
      float sv = w0*fi[x0i] + w1*fi[x1i];
      const float* wr = wk + i*64;
#pragma unroll
      for (int o = 0; o < 64; o++) acc[o] += sv * wr[o];
    }
  }
  float* dst = out + (size_t)b*Cq*HWq + p;
#pragma unroll
  for (int o = 0; o < 64; o++) dst[(size_t)o*HWq] = acc[o];
}

// ---------------------------------------------------------------------------
// GroupNorm stats + finalize + combine + final 1x1 + SiLU
// ---------------------------------------------------------------------------
__global__ __launch_bounds__(256) void gnstats_kernel(const float* __restrict__ h_ds,
                                                      const float* __restrict__ v_ds,
                                                      float* __restrict__ stats)
{
  int plane = blockIdx.x;
  int buf = plane >> 7;
  int rem = plane & 127;
  const float* src = (buf ? v_ds : h_ds) + (size_t)rem*HWq;
  float s = 0.f, s2 = 0.f;
  for (int i = threadIdx.x; i < HWq; i += 256) {
    float v = src[i];
    s += v; s2 += v*v;
  }
  __shared__ float red[2][4];
  for (int off = 32; off; off >>= 1) {
    s  += __shfl_down(s, off);
    s2 += __shfl_down(s2, off);
  }
  if ((threadIdx.x & 63) == 0) { red[0][threadIdx.x >> 6] = s; red[1][threadIdx.x >> 6] = s2; }
  __syncthreads();
  if (threadIdx.x == 0) {
    s  = red[0][0] + red[0][1] + red[0][2] + red[0][3];
    s2 = red[1][0] + red[1][1] + red[1][2] + red[1][3];
    stats[plane*2 + 0] = s;
    stats[plane*2 + 1] = s2;
  }
}

__global__ __launch_bounds__(256) void gnfinal_kernel(const float* __restrict__ stats,
                                                      const float* __restrict__ h_gn_g, const float* __restrict__ h_gn_b,
                                                      const float* __restrict__ v_gn_g, const float* __restrict__ v_gn_b,
                                                      float* __restrict__ gnAB)
{
  int t = threadIdx.x;
  int buf = t >> 7, ch = t & 63;
  int base = t & ~3;
  float sum = 0.f, ss = 0.f;
#pragma unroll
  for (int q = 0; q < 4; q++) { sum += stats[(base+q)*2]; ss += stats[(base+q)*2 + 1]; }
  const float n = 4.f * HWq;
  float mean = sum / n;
  float var = ss / n - mean*mean;
  float gg = (buf ? v_gn_g : h_gn_g)[ch];
  float bb = (buf ? v_gn_b : h_gn_b)[ch];
  float A = gg / sqrtf(var + 1e-5f);
  gnAB[t*2 + 0] = A;
  gnAB[t*2 + 1] = bb - mean*A;
}

__global__ __launch_bounds__(256) void combine_kernel(const float* __restrict__ h_ds,
                                                      const float* __restrict__ v_ds,
                                                      const float* __restrict__ x1,
                                                      const float* __restrict__ gnAB,
                                                      float* __restrict__ comb)
{
  size_t idx = (size_t)blockIdx.x*256 + threadIdx.x;
  int plane = (int)(idx / HWq);
  int ih = plane*2;
  int iv = (128 + plane)*2;
  float hv = h_ds[idx]*gnAB[ih] + gnAB[ih+1]; hv = fmaxf(hv, 0.f);
  float vv = v_ds[idx]*gnAB[iv] + gnAB[iv+1]; vv = fmaxf(vv, 0.f);
  comb[idx] = hv + vv + x1[idx];
}

__global__ __launch_bounds__(256) void final_kernel(const float* __restrict__ comb,
                                                    const float* __restrict__ lwT,
                                                    const float* __restrict__ lbO,
                                                    float* __restrict__ out)
{
  int b = blockIdx.y;
  int p = blockIdx.x*256 + threadIdx.x;
  const float* cb = comb + (size_t)b*Cq*HWq + p;
  float acc[64];
#pragma unroll
  for (int o = 0; o < 64; o++) acc[o] = 0.f;
  for (int i = 0; i < 64; i++) {
    float cv = cb[(size_t)i*HWq];
    const float* wr = lwT + i*64;
#pragma unroll
    for (int o = 0; o < 64; o++) acc[o] += cv * wr[o];
  }
  float* dst = out + (size_t)b*Cq*HWq + p;
#pragma unroll
  for (int o = 0; o < 64; o++) {
    float yv = acc[o] + lbO[o];
    dst[(size_t)o*HWq] = yv / (1.f + expf(-yv));
  }
}

// ---------------------------------------------------------------------------
extern "C" void kernel_launch(void* const* d_in, const int* in_sizes, int n_in,
                              void* d_out, int out_size, void* d_ws, size_t ws_size,
                              hipStream_t stream)
{
  const float* x       = (const float*)d_in[0];
  const float* w_first = (const float*)d_in[1];
  float* ws = (float*)d_ws;

  float* bufA = ws;            // conv7 out -> hfeat -> comb
  float* bufB = ws + Nq;       // rowsum -> vfeat
  float* x1   = ws + 2*Nq;
  float* h_ds = ws + 3*Nq;     // ALSO xpack (f16 hi/lo) before einsum_h runs
  float* v_ds = ws + 4*Nq;
  size_t off = 5*Nq;
  float* hcum  = ws + off; off += (size_t)Bq*7*HWq;
  float* vcum  = ws + off; off += (size_t)Bq*7*HWq;
  float* wEffH = ws + off; off += 64*19;
  float* bEffH = ws + off; off += 64;
  float* wEffV = ws + off; off += 64*19;
  float* bEffV = ws + off; off += 64;
  float* wtH   = ws + off; off += 64*64*7;
  float* wtV   = ws + off; off += 64*64*7;
  float* wOffH = ws + off; off += 9*64*8;
  float* bOffH = ws + off; off += 8;
  float* wOffV = ws + off; off += 9*64*8;
  float* bOffV = ws + off; off += 8;
  float* lwT   = ws + off; off += 64*64;
  float* lbO   = ws + off; off += 64;
  float* stats = ws + off; off += 512;
  float* gnAB  = ws + off; off += 512;
  unsigned short* wpack = (unsigned short*)(ws + off); off += 2*49*2*64*32/2 + 16;
  unsigned short* xpack = (unsigned short*)h_ds;   // Nq floats = exactly the f16-pair pack

  prep_small_kernel<<<dim3(1), dim3(256), 0, stream>>>(
      (const float*)d_in[2],  (const float*)d_in[3],  (const float*)d_in[4],  (const float*)d_in[5],
      (const float*)d_in[6],  (const float*)d_in[7],
      (const float*)d_in[8],  (const float*)d_in[9],  (const float*)d_in[10], (const float*)d_in[11],
      (const float*)d_in[12], (const float*)d_in[13],
      (const float*)d_in[14], (const float*)d_in[15], (const float*)d_in[16], (const float*)d_in[17],
      (const float*)d_in[18], (const float*)d_in[19],
      (const float*)d_in[24], (const float*)d_in[25], (const float*)d_in[26], (const float*)d_in[27],
      (const float*)d_in[28], (const float*)d_in[29],
      (const float*)d_in[34], (const float*)d_in[35], (const float*)d_in[36], (const float*)d_in[37],
      (const float*)d_in[38],
      wEffH, bEffH, wEffV, bEffV, wOffH, bOffH, wOffV, bOffV, lwT, lbO);

  prep_big_kernel<<<dim3(64), dim3(256), 0, stream>>>(
      w_first, (const float*)d_in[20], (const float*)d_in[30], wtH, wtV, wpack);

  tof16_pack_kernel<<<dim3(Hq, Bq), dim3(192), 0, stream>>>(x, xpack);
  conv7_mfma_kernel<<<dim3(4, 64, 2), dim3(192), 0, stream>>>(xpack, wpack, bufA);

  pool_row_kernel<<<dim3(18432), dim3(256), 0, stream>>>(bufA, bufB);
  pool_col_kernel<<<dim3(18432), dim3(256), 0, stream>>>(bufB, x1);

  dw_h_kernel<<<dim3(144, 64, 2), dim3(256), 0, stream>>>(x1, wEffH, bEffH,
      (const float*)d_in[2], (const float*)d_in[3], (const float*)d_in[4], (const float*)d_in[5],
      (const float*)d_in[6], (const float*)d_in[7], bufA);
  dw_v_kernel<<<dim3(144, 64, 2), dim3(256), 0, stream>>>(x1, wEffV, bEffV,
      (const float*)d_in[8], (const float*)d_in[9], (const float*)d_in[10], (const float*)d_in[11],
      (const float*)d_in[12], (const float*)d_in[13], bufB);

  off_cum_kernel<<<dim3(144, 2), dim3(256), 0, stream>>>(bufA, wOffH, bOffH, hcum);
  off_cum_kernel<<<dim3(144, 2), dim3(256), 0, stream>>>(bufB, wOffV, bOffV, vcum);

  einsum_h_kernel<<<dim3(144, 2), dim3(256), 0, stream>>>(bufA, hcum, wtH, (const float*)d_in[21], h_ds);
  einsum_v_kernel<<<dim3(144, 2), dim3(256), 0, stream>>>(bufB, vcum, wtV, (const float*)d_in[31], v_ds);

  gnstats_kernel<<<dim3(256), dim3(256), 0, stream>>>(h_ds, v_ds, stats);
  gnfinal_kernel<<<dim3(1), dim3(256), 0, stream>>>(stats,
      (const float*)d_in[22], (const float*)d_in[23],
      (const float*)d_in[32], (const float*)d_in[33], gnAB);

  combine_kernel<<<dim3(18432), dim3(256), 0, stream>>>(h_ds, v_ds, x1, gnAB, bufA);
  final_kernel<<<dim3(144, 2), dim3(256), 0, stream>>>(bufA, lwT, lbO, (float*)d_out);
}

// Round 6
// 840.308 us; speedup vs baseline: 2.2130x; 1.2329x over previous
//
#include <hip/hip_runtime.h>
#include <hip/hip_bf16.h>
#include <hip/hip_fp16.h>
#include <math.h>

#define Bq 2
#define Cq 64
#define Hq 192
#define Wq 192
#define HWq (Hq*Wq)            // 36864
#define Nq ((size_t)Bq*Cq*HWq) // 4718592

typedef __attribute__((ext_vector_type(8))) _Float16 f16x8;
typedef __attribute__((ext_vector_type(4))) float f32x4;

__device__ inline unsigned short h2us(__half h) {
  union { __half h; unsigned short u; } v; v.h = h; return v.u;
}

// ---------------------------------------------------------------------------
// Small prep (1 block): fold BN, compose depthwise chain (interior 19-tap),
// offset conv fold, last 1x1 fold.
// ---------------------------------------------------------------------------
__global__ __launch_bounds__(256) void prep_small_kernel(
    const float* hc1_w, const float* hc1_b, const float* hc2_w, const float* hc2_b,
    const float* hc3_w, const float* hc3_b,
    const float* vc1_w, const float* vc1_b, const float* vc2_w, const float* vc2_b,
    const float* vc3_w, const float* vc3_b,
    const float* h_off_w, const float* h_off_b, const float* h_bn_g, const float* h_bn_b,
    const float* h_bn_m, const float* h_bn_v,
    const float* v_off_w, const float* v_off_b, const float* v_bn_g, const float* v_bn_b,
    const float* v_bn_m, const float* v_bn_v,
    const float* last_w, const float* last_g, const float* last_b, const float* last_m,
    const float* last_v,
    float* wEffH, float* bEffH, float* wEffV, float* bEffV,
    float* wOffH, float* bOffH, float* wOffV, float* bOffV,
    float* lwT, float* lbO)
{
  int t = threadIdx.x;
  if (t < 128) {
    int ch = t & 63;
    bool ish = t < 64;
    const float* w1 = (ish ? hc1_w : vc1_w) + ch*9;
    const float* w2 = (ish ? hc2_w : vc2_w) + ch*7;
    const float* w3 = (ish ? hc3_w : vc3_w) + ch*5;
    float t15[15];
    for (int s = 0; s < 15; s++) {
      float a = 0.f;
      for (int j = 0; j < 9; j++) { int k2 = s - j; if (k2 >= 0 && k2 < 7) a += w1[j]*w2[k2]; }
      t15[s] = a;
    }
    float* we = (ish ? wEffH : wEffV) + ch*19;
    for (int s = 0; s < 19; s++) {
      float a = 0.f;
      for (int j = 0; j < 15; j++) { int k3 = s - j; if (k3 >= 0 && k3 < 5) a += t15[j]*w3[k3]; }
      we[s] = a;
    }
    float S2 = 0.f, S3 = 0.f;
    for (int j = 0; j < 7; j++) S2 += w2[j];
    for (int j = 0; j < 5; j++) S3 += w3[j];
    float b1 = (ish ? hc1_b : vc1_b)[ch];
    float b2 = (ish ? hc2_b : vc2_b)[ch];
    float b3 = (ish ? hc3_b : vc3_b)[ch];
    (ish ? bEffH : bEffV)[ch] = b1*S2*S3 + b2*S3 + b3;
  }
  for (int idx = t; idx < 9*64*7; idx += 256) {
    int tap = idx / 448; int rem = idx % 448; int i = rem / 7; int m = rem % 7;
    float invh = h_bn_g[m] / sqrtf(h_bn_v[m] + 1e-5f);
    wOffH[(tap*64 + i)*8 + m] = h_off_w[(m*64 + i)*9 + tap] * invh;
    float invv = v_bn_g[7+m] / sqrtf(v_bn_v[7+m] + 1e-5f);
    wOffV[(tap*64 + i)*8 + m] = v_off_w[((7+m)*64 + i)*9 + tap] * invv;
  }
  if (t < 7) {
    float invh = h_bn_g[t] / sqrtf(h_bn_v[t] + 1e-5f);
    bOffH[t] = h_off_b[t]*invh + h_bn_b[t] - h_bn_m[t]*invh;
    float invv = v_bn_g[7+t] / sqrtf(v_bn_v[7+t] + 1e-5f);
    bOffV[t] = v_off_b[7+t]*invv + v_bn_b[7+t] - v_bn_m[7+t]*invv;
  }
  for (int idx = t; idx < 4096; idx += 256) {
    int o = idx % 64; int i = idx / 64;
    float inv = last_g[o] / sqrtf(last_v[o] + 1e-3f);
    lwT[i*64 + o] = last_w[o*64 + i] * inv;
  }
  if (t < 64) {
    float inv = last_g[t] / sqrtf(last_v[t] + 1e-3f);
    lbO[t] = last_b[t] - last_m[t]*inv;
  }
}

// ---------------------------------------------------------------------------
// Border prep: for the 18 border positions the sequential 9->7->5 chain with
// zero-padded INTERMEDIATES is still linear per position -> compute its exact
// 19-tap weights + bias by impulse response. wB[branch][ch][cls(18)][20].
// cls 0..8 => pos 0..8 ; cls 9..17 => pos 183..191.
// ---------------------------------------------------------------------------
__global__ __launch_bounds__(256) void prep_border_kernel(
    const float* hc1_w, const float* hc1_b, const float* hc2_w, const float* hc2_b,
    const float* hc3_w, const float* hc3_b,
    const float* vc1_w, const float* vc1_b, const float* vc2_w, const float* vc2_b,
    const float* vc3_w, const float* vc3_b,
    float* wB)
{
  int tid = blockIdx.x*256 + threadIdx.x;
  if (tid >= 2*64*18) return;
  int cls = tid % 18;
  int ch  = (tid / 18) % 64;
  int br  = tid / (18*64);
  int c = (cls < 9) ? cls : cls + 174;       // 183..191
  const float* w1 = (br==0 ? hc1_w : vc1_w) + ch*9;
  const float* w2 = (br==0 ? hc2_w : vc2_w) + ch*7;
  const float* w3 = (br==0 ? hc3_w : vc3_w) + ch*5;
  float b1 = (br==0 ? hc1_b : vc1_b)[ch];
  float b2 = (br==0 ? hc2_b : vc2_b)[ch];
  float b3 = (br==0 ? hc3_b : vc3_b)[ch];
  float* dst = wB + ((size_t)(br*64 + ch)*18 + cls)*20;
  for (int cse = 0; cse < 20; cse++) {
    bool basis = (cse < 19);
    int fd = c + cse - 9;                    // impulse position (basis case)
    float B1 = basis ? 0.f : b1, B2 = basis ? 0.f : b2, B3 = basis ? 0.f : b3;
    float o3 = B3;
    for (int m = 0; m < 5; m++) {
      int d = c + m - 2;
      if (d < 0 || d >= Wq) continue;
      float o2 = B2;
      for (int k = 0; k < 7; k++) {
        int e = d + k - 3;
        if (e < 0 || e >= Wq) continue;
        float o1 = B1;
        if (basis) {
          int tp = fd - e + 4;               // stage-1 tap hitting the impulse
          if (tp >= 0 && tp < 9 && fd >= 0 && fd < Wq) o1 += w1[tp];
        }
        o2 += o1 * w2[k];
      }
      o3 += o2 * w3[m];
    }
    dst[cse] = o3;                           // cse<19: weight; cse==19: bias
  }
}

// ---------------------------------------------------------------------------
// Big prep (many blocks): dsc weight transpose + w_first f16 hi/lo pack.
// wpack layout: [h(2)][tap(49)][hl(2)][oc(64)][ch(32)] f16.
// ---------------------------------------------------------------------------
__global__ __launch_bounds__(256) void prep_big_kernel(
    const float* __restrict__ w_first,
    const float* __restrict__ h_dsc_w, const float* __restrict__ v_dsc_w,
    float* __restrict__ wtH, float* __restrict__ wtV,
    unsigned short* __restrict__ wpack)
{
  int tid = blockIdx.x*256 + threadIdx.x;
  int nthr = gridDim.x*256;
  for (int idx = tid; idx < 64*64*7; idx += nthr) {
    int o = idx / 448; int rem = idx % 448; int i = rem / 7; int k = rem % 7;
    wtH[(k*64 + i)*64 + o] = h_dsc_w[idx];
    wtV[(k*64 + i)*64 + o] = v_dsc_w[idx];
  }
  for (int e = tid; e < 2*49*2*64*32; e += nthr) {
    int ch  = e & 31;
    int oc  = (e >> 5) & 63;
    int hl  = (e >> 11) & 1;
    int rest = e >> 12;
    int tap = rest % 49;
    int h   = rest / 49;
    float wv = w_first[((size_t)oc*64 + h*32 + ch)*49 + tap];
    __half hh = __float2half(wv);
    unsigned short us;
    if (!hl) us = h2us(hh);
    else { float rr = wv - __half2float(hh); us = h2us(__float2half(rr)); }
    wpack[e] = us;
  }
}

// ---------------------------------------------------------------------------
// x (NCHW f32) -> xpack: per pixel 16 granules of 8 f16:
// [h(2)][hl(2)][g8(4)] x 8 ch. One block per (row, batch).
// ---------------------------------------------------------------------------
__global__ __launch_bounds__(192) void tof16_pack_kernel(const float* __restrict__ x,
                                                         unsigned short* __restrict__ xpack)
{
  __shared__ unsigned int s[192*64];
  int r = blockIdx.x, b = blockIdx.y;
  int t = threadIdx.x;
  for (int ch = 0; ch < 64; ch++) {
    float v = x[((size_t)(b*64+ch)*Hq + r)*Wq + t];
    __half hh = __float2half(v);
    float rr = v - __half2float(hh);
    __half hl = __float2half(rr);
    unsigned int pk = (unsigned int)h2us(hh) | ((unsigned int)h2us(hl) << 16);
    s[t*64 + (ch ^ (t & 31))] = pk;
  }
  __syncthreads();
  unsigned short* dst = xpack + ((size_t)b*Hq + r)*Wq*128;
  for (int i = 0; i < 16; i++) {
    int gidx = i*192 + t;
    int c = gidx >> 4, sub = gidx & 15;
    int h = sub >> 3, hl = (sub >> 2) & 1, g8 = sub & 3;
    unsigned short tmp[8];
#pragma unroll
    for (int j = 0; j < 8; j++) {
      int ch = h*32 + g8*8 + j;
      unsigned int u = s[c*64 + (ch ^ (c & 31))];
      tmp[j] = hl ? (unsigned short)(u >> 16) : (unsigned short)(u & 0xffff);
    }
    uint4 v;
    v.x = (unsigned int)tmp[0] | ((unsigned int)tmp[1] << 16);
    v.y = (unsigned int)tmp[2] | ((unsigned int)tmp[3] << 16);
    v.z = (unsigned int)tmp[4] | ((unsigned int)tmp[5] << 16);
    v.w = (unsigned int)tmp[6] | ((unsigned int)tmp[7] << 16);
    *(uint4*)(dst + (size_t)gidx*8) = v;
  }
}

// ---------------------------------------------------------------------------
// 7x7 conv 64->64 pad 3, MFMA implicit GEMM, f16 hi/lo 3-pass.
// ---------------------------------------------------------------------------
__global__ __launch_bounds__(192) void conv7_mfma_kernel(
    const unsigned short* __restrict__ xpack,
    const unsigned short* __restrict__ wpack,
    float* __restrict__ out)
{
  __shared__ __align__(16) unsigned short sA[9*54*64];
  int ct = blockIdx.x;
  int rt = blockIdx.y;
  int b  = blockIdx.z;
  int r0 = rt*3, c0 = ct*48;
  int t = threadIdx.x;
  int w = t >> 6;
  int l = t & 63;
  int l15 = l & 15, lg = l >> 4;

  f32x4 acc[3][4];
#pragma unroll
  for (int i = 0; i < 3; i++)
#pragma unroll
    for (int j = 0; j < 4; j++) acc[i][j] = (f32x4){0.f,0.f,0.f,0.f};

  for (int h = 0; h < 2; h++) {
    __syncthreads();
    for (int idx = t; idx < 9*54*8; idx += 192) {
      int g = idx & 7, pix = idx >> 3;
      int row = pix / 54, col = pix % 54;
      int gr = r0 - 3 + row, gc = c0 - 3 + col;
      uint4 v = {0u,0u,0u,0u};
      if (gr >= 0 && gr < Hq && gc >= 0 && gc < Wq)
        v = *(const uint4*)(xpack + (((size_t)b*Hq + gr)*Wq + gc)*128 + (h*8 + g)*8);
      ((uint4*)sA)[(row*54 + col)*8 + (g ^ (col & 7))] = v;
    }
    __syncthreads();
    const unsigned short* wb = wpack + (size_t)h*49*4096;
    for (int tap = 0; tap < 49; tap++) {
      int dy = tap / 7, dx = tap % 7;
      f16x8 bh[4], bl[4];
#pragma unroll
      for (int tb = 0; tb < 4; tb++) {
        bh[tb] = *(const f16x8*)(wb + (size_t)tap*4096 + (tb*16 + l15)*32 + lg*8);
        bl[tb] = *(const f16x8*)(wb + (size_t)tap*4096 + 2048 + (tb*16 + l15)*32 + lg*8);
      }
      int arow = w + dy;
      f16x8 ah[3], al[3];
#pragma unroll
      for (int ta = 0; ta < 3; ta++) {
        int col = ta*16 + l15 + dx;
        const uint4* base = (const uint4*)sA + (arow*54 + col)*8;
        ah[ta] = *(const f16x8*)(base + (lg ^ (col & 7)));
        al[ta] = *(const f16x8*)(base + ((lg + 4) ^ (col & 7)));
      }
#pragma unroll
      for (int ta = 0; ta < 3; ta++)
#pragma unroll
        for (int tb = 0; tb < 4; tb++) {
          acc[ta][tb] = __builtin_amdgcn_mfma_f32_16x16x32_f16(ah[ta], bh[tb], acc[ta][tb], 0, 0, 0);
          acc[ta][tb] = __builtin_amdgcn_mfma_f32_16x16x32_f16(ah[ta], bl[tb], acc[ta][tb], 0, 0, 0);
          acc[ta][tb] = __builtin_amdgcn_mfma_f32_16x16x32_f16(al[ta], bh[tb], acc[ta][tb], 0, 0, 0);
        }
    }
  }
#pragma unroll
  for (int tb = 0; tb < 4; tb++) {
    int oc = tb*16 + l15;
    float* dst = out + ((size_t)(b*64 + oc)*Hq + (r0 + w))*Wq + c0;
#pragma unroll
    for (int ta = 0; ta < 3; ta++) {
      f32x4 v = acc[ta][tb];
      *(float4*)(dst + ta*16 + lg*4) = make_float4(v[0], v[1], v[2], v[3]);
    }
  }
}

// ---------------------------------------------------------------------------
// Separable 7x7 avg pool (sum with zero pad, /49)
// ---------------------------------------------------------------------------
__global__ __launch_bounds__(256) void pool_row_kernel(const float* __restrict__ in, float* __restrict__ out)
{
  int idx = blockIdx.x*256 + threadIdx.x;
  int c = idx % Wq;
  int base = idx - c;
  float s = 0.f;
#pragma unroll
  for (int dc = -3; dc <= 3; dc++) {
    int cc = c + dc;
    if (cc >= 0 && cc < Wq) s += in[base + cc];
  }
  out[idx] = s;
}

__global__ __launch_bounds__(256) void pool_col_kernel(const float* __restrict__ in, float* __restrict__ out)
{
  int idx = blockIdx.x*256 + threadIdx.x;
  int c = idx % Wq;
  int r = (idx / Wq) % Hq;
  int plane = idx / HWq;
  float s = 0.f;
#pragma unroll
  for (int dr = -3; dr <= 3; dr++) {
    int rr = r + dr;
    if (rr >= 0 && rr < Hq) s += in[(size_t)plane*HWq + rr*Wq + c];
  }
  out[idx] = s * (1.f/49.f);
}

// ---------------------------------------------------------------------------
// Depthwise chain as uniform 19-tap conv for ALL pixels:
// row class 0..17 = border (exact composed clipped weights), 18 = interior.
// ---------------------------------------------------------------------------
__global__ __launch_bounds__(256) void dw_h_kernel(const float* __restrict__ x1,
                                                   const float* __restrict__ wEff,
                                                   const float* __restrict__ bEff,
                                                   const float* __restrict__ wB,
                                                   float* __restrict__ out)
{
  __shared__ float sW[19][20];
  int b = blockIdx.z, ch = blockIdx.y;
  int t = threadIdx.x;
  for (int i = t; i < 380; i += 256) {
    int row = i / 20, jj = i % 20;
    float v;
    if (row < 18) v = wB[((size_t)ch*18 + row)*20 + jj];
    else v = (jj < 19) ? wEff[ch*19 + jj] : bEff[ch];
    sW[row][jj] = v;
  }
  __syncthreads();
  int p = blockIdx.x*256 + t;
  int r = p / Wq, c = p % Wq;
  const float* src = x1 + (size_t)(b*Cq + ch)*HWq + r*Wq;
  int row = (c < 9) ? c : ((c >= Wq-9) ? (c - 174) : 18);
  float s = sW[row][19];
#pragma unroll
  for (int j = 0; j < 19; j++) {
    int idx = min(max(c + j - 9, 0), Wq-1);
    s += src[idx] * sW[row][j];
  }
  out[(size_t)(b*Cq + ch)*HWq + p] = s;
}

__global__ __launch_bounds__(256) void dw_v_kernel(const float* __restrict__ x1,
                                                   const float* __restrict__ wEff,
                                                   const float* __restrict__ bEff,
                                                   const float* __restrict__ wB,
                                                   float* __restrict__ out)
{
  __shared__ float sW[19][20];
  int b = blockIdx.z, ch = blockIdx.y;
  int t = threadIdx.x;
  for (int i = t; i < 380; i += 256) {
    int row = i / 20, jj = i % 20;
    float v;
    if (row < 18) v = wB[((size_t)ch*18 + row)*20 + jj];
    else v = (jj < 19) ? wEff[ch*19 + jj] : bEff[ch];
    sW[row][jj] = v;
  }
  __syncthreads();
  int p = blockIdx.x*256 + t;
  int r = p / Wq, c = p % Wq;
  const float* src = x1 + (size_t)(b*Cq + ch)*HWq + c;
  int row = (r < 9) ? r : ((r >= Hq-9) ? (r - 174) : 18);
  float s = sW[row][19];
#pragma unroll
  for (int j = 0; j < 19; j++) {
    int idx = min(max(r + j - 9, 0), Hq-1);
    s += src[idx*Wq] * sW[row][j];
  }
  out[(size_t)(b*Cq + ch)*HWq + p] = s;
}

// ---------------------------------------------------------------------------
// Offset conv (3x3, 64->7, BN folded) + tanh + cum_offset
// ---------------------------------------------------------------------------
__global__ __launch_bounds__(256) void off_cum_kernel(const float* __restrict__ feat,
                                                      const float* __restrict__ wOff,
                                                      const float* __restrict__ bOff,
                                                      float* __restrict__ cum)
{
  int b = blockIdx.y;
  int p = blockIdx.x*256 + threadIdx.x;
  int r = p / Wq, c = p % Wq;
  float tv[7];
#pragma unroll
  for (int m = 0; m < 7; m++) tv[m] = bOff[m];
  const float* fb = feat + (size_t)b*Cq*HWq;
  for (int tap = 0; tap < 9; tap++) {
    int dy = tap/3 - 1, dx = tap%3 - 1;
    int rr = r + dy, cc = c + dx;
    if (rr < 0 || rr >= Hq || cc < 0 || cc >= Wq) continue;
    const float* fp = fb + rr*Wq + cc;
    const float* wp = wOff + tap*512;
    for (int i = 0; i < 64; i++) {
      float fv = fp[(size_t)i*HWq];
#pragma unroll
      for (int m = 0; m < 7; m++) tv[m] += fv * wp[i*8 + m];
    }
  }
#pragma unroll
  for (int m = 0; m < 7; m++) tv[m] = tanhf(tv[m]);
  float c0 = tv[0], c1 = tv[1] + tv[2], c2 = tv[2], c3 = 0.f;
  float c4 = tv[4], c5 = tv[4] + tv[5], c6 = tv[6];
  size_t bb = (size_t)b*7*HWq + p;
  cum[bb + 0*HWq] = c0; cum[bb + 1*HWq] = c1; cum[bb + 2*HWq] = c2;
  cum[bb + 3*HWq] = c3; cum[bb + 4*HWq] = c4; cum[bb + 5*HWq] = c5;
  cum[bb + 6*HWq] = c6;
}

// ---------------------------------------------------------------------------
// Deformable sample + einsum, morph=0 (h)
// ---------------------------------------------------------------------------
__global__ __launch_bounds__(256) void einsum_h_kernel(const float* __restrict__ feat,
                                                       const float* __restrict__ cum,
                                                       const float* __restrict__ wt,
                                                       const float* __restrict__ dsc_b,
                                                       float* __restrict__ out)
{
  int b = blockIdx.y;
  int p = blockIdx.x*256 + threadIdx.x;
  int r = p / Wq, c = p % Wq;
  float acc[64];
#pragma unroll
  for (int o = 0; o < 64; o++) acc[o] = dsc_b[o];
  const float* fb = feat + (size_t)b*Cq*HWq;
  for (int k = 0; k < 7; k++) {
    int xi = c + k - 3;
    if (xi < 0 || xi > Wq-1) continue;
    float y = (float)r + cum[((size_t)(b*7 + k))*HWq + p];
    float y0 = floorf(y);
    int y0q = (int)y0;
    int y0i = min(max(y0q, 0), Hq-1);
    int y1i = min(max(y0q + 1, 0), Hq-1);
    float y0f = fminf(fmaxf(y0, 0.f), (float)Hq);
    float y1f = fminf(fmaxf(y0 + 1.f, 0.f), (float)Hq);
    float w0 = y1f - y, w1 = y - y0f;
    const float* f0 = fb + y0i*Wq + xi;
    const float* f1 = fb + y1i*Wq + xi;
    const float* wk = wt + k*4096;
    for (int i = 0; i < 64; i++) {
      float sv = w0*f0[(size_t)i*HWq] + w1*f1[(size_t)i*HWq];
      const float* wr = wk + i*64;
#pragma unroll
      for (int o = 0; o < 64; o++) acc[o] += sv * wr[o];
    }
  }
  float* dst = out + (size_t)b*Cq*HWq + p;
#pragma unroll
  for (int o = 0; o < 64; o++) dst[(size_t)o*HWq] = acc[o];
}

// morph=1 (v)
__global__ __launch_bounds__(256) void einsum_v_kernel(const float* __restrict__ feat,
                                                       const float* __restrict__ cum,
                                                       const float* __restrict__ wt,
                                                       const float* __restrict__ dsc_b,
                                                       float* __restrict__ out)
{
  int b = blockIdx.y;
  int p = blockIdx.x*256 + threadIdx.x;
  int r = p / Wq, c = p % Wq;
  float acc[64];
#pragma unroll
  for (int o = 0; o < 64; o++) acc[o] = dsc_b[o];
  const float* fb = feat + (size_t)b*Cq*HWq;
  for (int k = 0; k < 7; k++) {
    int yi = r + k - 3;
    if (yi < 0 || yi > Hq-1) continue;
    float xf = (float)c + cum[((size_t)(b*7 + k))*HWq + p];
    float x0 = floorf(xf);
    int x0q = (int)x0;
    int x0i = min(max(x0q, 0), Wq-1);
    int x1i = min(max(x0q + 1, 0), Wq-1);
    float x0f = fminf(fmaxf(x0, 0.f), (float)Wq);
    float x1f = fminf(fmaxf(x0 + 1.f, 0.f), (float)Wq);
    float w0 = x1f - xf, w1 = xf - x0f;
    const float* f0 = fb + yi*Wq;
    const float* wk = wt + k*4096;
    for (int i = 0; i < 64; i++) {
      const float* fi = f0 + (size_t)i*HWq;
      float sv = w0*fi[x0i] + w1*fi[x1i];
      const float* wr = wk + i*64;
#pragma unroll
      for (int o = 0; o < 64; o++) acc[o] += sv * wr[o];
    }
  }
  float* dst = out + (size_t)b*Cq*HWq + p;
#pragma unroll
  for (int o = 0; o < 64; o++) dst[(size_t)o*HWq] = acc[o];
}

// ---------------------------------------------------------------------------
// GroupNorm stats + finalize + combine + final 1x1 + SiLU
// ---------------------------------------------------------------------------
__global__ __launch_bounds__(256) void gnstats_kernel(const float* __restrict__ h_ds,
                                                      const float* __restrict__ v_ds,
                                                      float* __restrict__ stats)
{
  int plane = blockIdx.x;
  int buf = plane >> 7;
  int rem = plane & 127;
  const float* src = (buf ? v_ds : h_ds) + (size_t)rem*HWq;
  float s = 0.f, s2 = 0.f;
  for (int i = threadIdx.x; i < HWq; i += 256) {
    float v = src[i];
    s += v; s2 += v*v;
  }
  __shared__ float red[2][4];
  for (int off = 32; off; off >>= 1) {
    s  += __shfl_down(s, off);
    s2 += __shfl_down(s2, off);
  }
  if ((threadIdx.x & 63) == 0) { red[0][threadIdx.x >> 6] = s; red[1][threadIdx.x >> 6] = s2; }
  __syncthreads();
  if (threadIdx.x == 0) {
    s  = red[0][0] + red[0][1] + red[0][2] + red[0][3];
    s2 = red[1][0] + red[1][1] + red[1][2] + red[1][3];
    stats[plane*2 + 0] = s;
    stats[plane*2 + 1] = s2;
  }
}

__global__ __launch_bounds__(256) void gnfinal_kernel(const float* __restrict__ stats,
                                                      const float* __restrict__ h_gn_g, const float* __restrict__ h_gn_b,
                                                      const float* __restrict__ v_gn_g, const float* __restrict__ v_gn_b,
                                                      float* __restrict__ gnAB)
{
  int t = threadIdx.x;
  int buf = t >> 7, ch = t & 63;
  int base = t & ~3;
  float sum = 0.f, ss = 0.f;
#pragma unroll
  for (int q = 0; q < 4; q++) { sum += stats[(base+q)*2]; ss += stats[(base+q)*2 + 1]; }
  const float n = 4.f * HWq;
  float mean = sum / n;
  float var = ss / n - mean*mean;
  float gg = (buf ? v_gn_g : h_gn_g)[ch];
  float bb = (buf ? v_gn_b : h_gn_b)[ch];
  float A = gg / sqrtf(var + 1e-5f);
  gnAB[t*2 + 0] = A;
  gnAB[t*2 + 1] = bb - mean*A;
}

__global__ __launch_bounds__(256) void combine_kernel(const float* __restrict__ h_ds,
                                                      const float* __restrict__ v_ds,
                                                      const float* __restrict__ x1,
                                                      const float* __restrict__ gnAB,
                                                      float* __restrict__ comb)
{
  size_t idx = (size_t)blockIdx.x*256 + threadIdx.x;
  int plane = (int)(idx / HWq);
  int ih = plane*2;
  int iv = (128 + plane)*2;
  float hv = h_ds[idx]*gnAB[ih] + gnAB[ih+1]; hv = fmaxf(hv, 0.f);
  float vv = v_ds[idx]*gnAB[iv] + gnAB[iv+1]; vv = fmaxf(vv, 0.f);
  comb[idx] = hv + vv + x1[idx];
}

__global__ __launch_bounds__(256) void final_kernel(const float* __restrict__ comb,
                                                    const float* __restrict__ lwT,
                                                    const float* __restrict__ lbO,
                                                    float* __restrict__ out)
{
  int b = blockIdx.y;
  int p = blockIdx.x*256 + threadIdx.x;
  const float* cb = comb + (size_t)b*Cq*HWq + p;
  float acc[64];
#pragma unroll
  for (int o = 0; o < 64; o++) acc[o] = 0.f;
  for (int i = 0; i < 64; i++) {
    float cv = cb[(size_t)i*HWq];
    const float* wr = lwT + i*64;
#pragma unroll
    for (int o = 0; o < 64; o++) acc[o] += cv * wr[o];
  }
  float* dst = out + (size_t)b*Cq*HWq + p;
#pragma unroll
  for (int o = 0; o < 64; o++) {
    float yv = acc[o] + lbO[o];
    dst[(size_t)o*HWq] = yv / (1.f + expf(-yv));
  }
}

// ---------------------------------------------------------------------------
extern "C" void kernel_launch(void* const* d_in, const int* in_sizes, int n_in,
                              void* d_out, int out_size, void* d_ws, size_t ws_size,
                              hipStream_t stream)
{
  const float* x       = (const float*)d_in[0];
  const float* w_first = (const float*)d_in[1];
  float* ws = (float*)d_ws;

  float* bufA = ws;            // conv7 out -> hfeat -> comb
  float* bufB = ws + Nq;       // rowsum -> vfeat
  float* x1   = ws + 2*Nq;
  float* h_ds = ws + 3*Nq;     // ALSO xpack (f16 hi/lo) before einsum_h runs
  float* v_ds = ws + 4*Nq;
  size_t off = 5*Nq;
  float* hcum  = ws + off; off += (size_t)Bq*7*HWq;
  float* vcum  = ws + off; off += (size_t)Bq*7*HWq;
  float* wEffH = ws + off; off += 64*19;
  float* bEffH = ws + off; off += 64;
  float* wEffV = ws + off; off += 64*19;
  float* bEffV = ws + off; off += 64;
  float* wtH   = ws + off; off += 64*64*7;
  float* wtV   = ws + off; off += 64*64*7;
  float* wOffH = ws + off; off += 9*64*8;
  float* bOffH = ws + off; off += 8;
  float* wOffV = ws + off; off += 9*64*8;
  float* bOffV = ws + off; off += 8;
  float* lwT   = ws + off; off += 64*64;
  float* lbO   = ws + off; off += 64;
  float* stats = ws + off; off += 512;
  float* gnAB  = ws + off; off += 512;
  float* wB    = ws + off; off += 2*64*18*20;   // border dw weights
  unsigned short* wpack = (unsigned short*)(ws + off); off += 2*49*2*64*32/2 + 16;
  unsigned short* xpack = (unsigned short*)h_ds;

  prep_small_kernel<<<dim3(1), dim3(256), 0, stream>>>(
      (const float*)d_in[2],  (const float*)d_in[3],  (const float*)d_in[4],  (const float*)d_in[5],
      (const float*)d_in[6],  (const float*)d_in[7],
      (const float*)d_in[8],  (const float*)d_in[9],  (const float*)d_in[10], (const float*)d_in[11],
      (const float*)d_in[12], (const float*)d_in[13],
      (const float*)d_in[14], (const float*)d_in[15], (const float*)d_in[16], (const float*)d_in[17],
      (const float*)d_in[18], (const float*)d_in[19],
      (const float*)d_in[24], (const float*)d_in[25], (const float*)d_in[26], (const float*)d_in[27],
      (const float*)d_in[28], (const float*)d_in[29],
      (const float*)d_in[34], (const float*)d_in[35], (const float*)d_in[36], (const float*)d_in[37],
      (const float*)d_in[38],
      wEffH, bEffH, wEffV, bEffV, wOffH, bOffH, wOffV, bOffV, lwT, lbO);

  prep_border_kernel<<<dim3(9), dim3(256), 0, stream>>>(
      (const float*)d_in[2],  (const float*)d_in[3],  (const float*)d_in[4],  (const float*)d_in[5],
      (const float*)d_in[6],  (const float*)d_in[7],
      (const float*)d_in[8],  (const float*)d_in[9],  (const float*)d_in[10], (const float*)d_in[11],
      (const float*)d_in[12], (const float*)d_in[13], wB);

  prep_big_kernel<<<dim3(64), dim3(256), 0, stream>>>(
      w_first, (const float*)d_in[20], (const float*)d_in[30], wtH, wtV, wpack);

  tof16_pack_kernel<<<dim3(Hq, Bq), dim3(192), 0, stream>>>(x, xpack);
  conv7_mfma_kernel<<<dim3(4, 64, 2), dim3(192), 0, stream>>>(xpack, wpack, bufA);

  pool_row_kernel<<<dim3(18432), dim3(256), 0, stream>>>(bufA, bufB);
  pool_col_kernel<<<dim3(18432), dim3(256), 0, stream>>>(bufB, x1);

  dw_h_kernel<<<dim3(144, 64, 2), dim3(256), 0, stream>>>(x1, wEffH, bEffH, wB, bufA);
  dw_v_kernel<<<dim3(144, 64, 2), dim3(256), 0, stream>>>(x1, wEffV, bEffV, wB + 64*18*20, bufB);

  off_cum_kernel<<<dim3(144, 2), dim3(256), 0, stream>>>(bufA, wOffH, bOffH, hcum);
  off_cum_kernel<<<dim3(144, 2), dim3(256), 0, stream>>>(bufB, wOffV, bOffV, vcum);

  einsum_h_kernel<<<dim3(144, 2), dim3(256), 0, stream>>>(bufA, hcum, wtH, (const float*)d_in[21], h_ds);
  einsum_v_kernel<<<dim3(144, 2), dim3(256), 0, stream>>>(bufB, vcum, wtV, (const float*)d_in[31], v_ds);

  gnstats_kernel<<<dim3(256), dim3(256), 0, stream>>>(h_ds, v_ds, stats);
  gnfinal_kernel<<<dim3(1), dim3(256), 0, stream>>>(stats,
      (const float*)d_in[22], (const float*)d_in[23],
      (const float*)d_in[32], (const float*)d_in[33], gnAB);

  combine_kernel<<<dim3(18432), dim3(256), 0, stream>>>(h_ds, v_ds, x1, gnAB, bufA);
  final_kernel<<<dim3(144, 2), dim3(256), 0, stream>>>(bufA, lwT, lbO, (float*)d_out);
}

// Round 7
// 761.013 us; speedup vs baseline: 2.4436x; 1.1042x over previous
//
#include <hip/hip_runtime.h>
#include <hip/hip_bf16.h>
#include <hip/hip_fp16.h>
#include <math.h>

#define Bq 2
#define Cq 64
#define Hq 192
#define Wq 192
#define HWq (Hq*Wq)            // 36864
#define Nq ((size_t)Bq*Cq*HWq) // 4718592

typedef __attribute__((ext_vector_type(8))) _Float16 f16x8;
typedef __attribute__((ext_vector_type(4))) float f32x4;

__device__ inline unsigned short h2us(__half h) {
  union { __half h; unsigned short u; } v; v.h = h; return v.u;
}

// ---------------------------------------------------------------------------
// Small prep (1 block)
// ---------------------------------------------------------------------------
__global__ __launch_bounds__(256) void prep_small_kernel(
    const float* hc1_w, const float* hc1_b, const float* hc2_w, const float* hc2_b,
    const float* hc3_w, const float* hc3_b,
    const float* vc1_w, const float* vc1_b, const float* vc2_w, const float* vc2_b,
    const float* vc3_w, const float* vc3_b,
    const float* h_off_w, const float* h_off_b, const float* h_bn_g, const float* h_bn_b,
    const float* h_bn_m, const float* h_bn_v,
    const float* v_off_w, const float* v_off_b, const float* v_bn_g, const float* v_bn_b,
    const float* v_bn_m, const float* v_bn_v,
    const float* last_w, const float* last_g, const float* last_b, const float* last_m,
    const float* last_v,
    float* wEffH, float* bEffH, float* wEffV, float* bEffV,
    float* wOffH, float* bOffH, float* wOffV, float* bOffV,
    float* lwT, float* lbO)
{
  int t = threadIdx.x;
  if (t < 128) {
    int ch = t & 63;
    bool ish = t < 64;
    const float* w1 = (ish ? hc1_w : vc1_w) + ch*9;
    const float* w2 = (ish ? hc2_w : vc2_w) + ch*7;
    const float* w3 = (ish ? hc3_w : vc3_w) + ch*5;
    float t15[15];
    for (int s = 0; s < 15; s++) {
      float a = 0.f;
      for (int j = 0; j < 9; j++) { int k2 = s - j; if (k2 >= 0 && k2 < 7) a += w1[j]*w2[k2]; }
      t15[s] = a;
    }
    float* we = (ish ? wEffH : wEffV) + ch*19;
    for (int s = 0; s < 19; s++) {
      float a = 0.f;
      for (int j = 0; j < 15; j++) { int k3 = s - j; if (k3 >= 0 && k3 < 5) a += t15[j]*w3[k3]; }
      we[s] = a;
    }
    float S2 = 0.f, S3 = 0.f;
    for (int j = 0; j < 7; j++) S2 += w2[j];
    for (int j = 0; j < 5; j++) S3 += w3[j];
    float b1 = (ish ? hc1_b : vc1_b)[ch];
    float b2 = (ish ? hc2_b : vc2_b)[ch];
    float b3 = (ish ? hc3_b : vc3_b)[ch];
    (ish ? bEffH : bEffV)[ch] = b1*S2*S3 + b2*S3 + b3;
  }
  for (int idx = t; idx < 9*64*7; idx += 256) {
    int tap = idx / 448; int rem = idx % 448; int i = rem / 7; int m = rem % 7;
    float invh = h_bn_g[m] / sqrtf(h_bn_v[m] + 1e-5f);
    wOffH[(tap*64 + i)*8 + m] = h_off_w[(m*64 + i)*9 + tap] * invh;
    float invv = v_bn_g[7+m] / sqrtf(v_bn_v[7+m] + 1e-5f);
    wOffV[(tap*64 + i)*8 + m] = v_off_w[((7+m)*64 + i)*9 + tap] * invv;
  }
  if (t < 7) {
    float invh = h_bn_g[t] / sqrtf(h_bn_v[t] + 1e-5f);
    bOffH[t] = h_off_b[t]*invh + h_bn_b[t] - h_bn_m[t]*invh;
    float invv = v_bn_g[7+t] / sqrtf(v_bn_v[7+t] + 1e-5f);
    bOffV[t] = v_off_b[7+t]*invv + v_bn_b[7+t] - v_bn_m[7+t]*invv;
  }
  for (int idx = t; idx < 4096; idx += 256) {
    int o = idx % 64; int i = idx / 64;
    float inv = last_g[o] / sqrtf(last_v[o] + 1e-3f);
    lwT[i*64 + o] = last_w[o*64 + i] * inv;
  }
  if (t < 64) {
    float inv = last_g[t] / sqrtf(last_v[t] + 1e-3f);
    lbO[t] = last_b[t] - last_m[t]*inv;
  }
}

// ---------------------------------------------------------------------------
// Border prep (impulse-response composed clipped 19-tap weights)
// ---------------------------------------------------------------------------
__global__ __launch_bounds__(256) void prep_border_kernel(
    const float* hc1_w, const float* hc1_b, const float* hc2_w, const float* hc2_b,
    const float* hc3_w, const float* hc3_b,
    const float* vc1_w, const float* vc1_b, const float* vc2_w, const float* vc2_b,
    const float* vc3_w, const float* vc3_b,
    float* wB)
{
  int tid = blockIdx.x*256 + threadIdx.x;
  if (tid >= 2*64*18) return;
  int cls = tid % 18;
  int ch  = (tid / 18) % 64;
  int br  = tid / (18*64);
  int c = (cls < 9) ? cls : cls + 174;
  const float* w1 = (br==0 ? hc1_w : vc1_w) + ch*9;
  const float* w2 = (br==0 ? hc2_w : vc2_w) + ch*7;
  const float* w3 = (br==0 ? hc3_w : vc3_w) + ch*5;
  float b1 = (br==0 ? hc1_b : vc1_b)[ch];
  float b2 = (br==0 ? hc2_b : vc2_b)[ch];
  float b3 = (br==0 ? hc3_b : vc3_b)[ch];
  float* dst = wB + ((size_t)(br*64 + ch)*18 + cls)*20;
  for (int cse = 0; cse < 20; cse++) {
    bool basis = (cse < 19);
    int fd = c + cse - 9;
    float B1 = basis ? 0.f : b1, B2 = basis ? 0.f : b2, B3 = basis ? 0.f : b3;
    float o3 = B3;
    for (int m = 0; m < 5; m++) {
      int d = c + m - 2;
      if (d < 0 || d >= Wq) continue;
      float o2 = B2;
      for (int k = 0; k < 7; k++) {
        int e = d + k - 3;
        if (e < 0 || e >= Wq) continue;
        float o1 = B1;
        if (basis) {
          int tp = fd - e + 4;
          if (tp >= 0 && tp < 9 && fd >= 0 && fd < Wq) o1 += w1[tp];
        }
        o2 += o1 * w2[k];
      }
      o3 += o2 * w3[m];
    }
    dst[cse] = o3;
  }
}

// ---------------------------------------------------------------------------
// Big prep: dsc weights -> f16 hi/lo MFMA pack [tap][kc][hl][oc][32]
//           + w_first f16 hi/lo pack for conv7.
// ---------------------------------------------------------------------------
__global__ __launch_bounds__(256) void prep_big_kernel(
    const float* __restrict__ w_first,
    const float* __restrict__ h_dsc_w, const float* __restrict__ v_dsc_w,
    unsigned short* __restrict__ wtpH, unsigned short* __restrict__ wtpV,
    unsigned short* __restrict__ wpack)
{
  int tid = blockIdx.x*256 + threadIdx.x;
  int nthr = gridDim.x*256;
  for (int idx = tid; idx < 7*2*2*64*32; idx += nthr) {
    int ch32 = idx & 31;
    int oc   = (idx >> 5) & 63;
    int hl   = (idx >> 11) & 1;
    int kc   = (idx >> 12) & 1;
    int tap  = idx >> 13;
    int i = kc*32 + ch32;
    float vh = h_dsc_w[oc*448 + i*7 + tap];
    float vv = v_dsc_w[oc*448 + i*7 + tap];
    _Float16 hh = (_Float16)vh;
    _Float16 hv = (_Float16)vv;
    unsigned short uh, uv;
    if (!hl) { uh = *(unsigned short*)&hh; uv = *(unsigned short*)&hv; }
    else {
      _Float16 lh = (_Float16)(vh - (float)hh);
      _Float16 lv = (_Float16)(vv - (float)hv);
      uh = *(unsigned short*)&lh; uv = *(unsigned short*)&lv;
    }
    wtpH[idx] = uh; wtpV[idx] = uv;
  }
  for (int e = tid; e < 2*49*2*64*32; e += nthr) {
    int ch  = e & 31;
    int oc  = (e >> 5) & 63;
    int hl  = (e >> 11) & 1;
    int rest = e >> 12;
    int tap = rest % 49;
    int h   = rest / 49;
    float wv = w_first[((size_t)oc*64 + h*32 + ch)*49 + tap];
    __half hh = __float2half(wv);
    unsigned short us;
    if (!hl) us = h2us(hh);
    else { float rr = wv - __half2float(hh); us = h2us(__float2half(rr)); }
    wpack[e] = us;
  }
}

// ---------------------------------------------------------------------------
// x (NCHW f32) -> xpack (conv7 layout): per pixel [h(2)][hl(2)][g8(4)] x 8 ch
// ---------------------------------------------------------------------------
__global__ __launch_bounds__(192) void tof16_pack_kernel(const float* __restrict__ x,
                                                         unsigned short* __restrict__ xpack)
{
  __shared__ unsigned int s[192*64];
  int r = blockIdx.x, b = blockIdx.y;
  int t = threadIdx.x;
  for (int ch = 0; ch < 64; ch++) {
    float v = x[((size_t)(b*64+ch)*Hq + r)*Wq + t];
    __half hh = __float2half(v);
    float rr = v - __half2float(hh);
    __half hl = __float2half(rr);
    unsigned int pk = (unsigned int)h2us(hh) | ((unsigned int)h2us(hl) << 16);
    s[t*64 + (ch ^ (t & 31))] = pk;
  }
  __syncthreads();
  unsigned short* dst = xpack + ((size_t)b*Hq + r)*Wq*128;
  for (int i = 0; i < 16; i++) {
    int gidx = i*192 + t;
    int c = gidx >> 4, sub = gidx & 15;
    int h = sub >> 3, hl = (sub >> 2) & 1, g8 = sub & 3;
    unsigned short tmp[8];
#pragma unroll
    for (int j = 0; j < 8; j++) {
      int ch = h*32 + g8*8 + j;
      unsigned int u = s[c*64 + (ch ^ (c & 31))];
      tmp[j] = hl ? (unsigned short)(u >> 16) : (unsigned short)(u & 0xffff);
    }
    uint4 v;
    v.x = (unsigned int)tmp[0] | ((unsigned int)tmp[1] << 16);
    v.y = (unsigned int)tmp[2] | ((unsigned int)tmp[3] << 16);
    v.z = (unsigned int)tmp[4] | ((unsigned int)tmp[5] << 16);
    v.w = (unsigned int)tmp[6] | ((unsigned int)tmp[7] << 16);
    *(uint4*)(dst + (size_t)gidx*8) = v;
  }
}

// ---------------------------------------------------------------------------
// feat (NCHW f32) -> fpack [px][hi64|lo64] f16
// ---------------------------------------------------------------------------
__global__ __launch_bounds__(192) void fpack_kernel(const float* __restrict__ in,
                                                    unsigned short* __restrict__ pack)
{
  __shared__ unsigned int s[192*64];
  int r = blockIdx.x, b = blockIdx.y;
  int t = threadIdx.x;
  for (int ch = 0; ch < 64; ch++) {
    float v = in[((size_t)(b*64+ch)*Hq + r)*Wq + t];
    __half hh = __float2half(v);
    float rr = v - __half2float(hh);
    __half hl = __float2half(rr);
    unsigned int pk = (unsigned int)h2us(hh) | ((unsigned int)h2us(hl) << 16);
    s[t*64 + (ch ^ (t & 31))] = pk;
  }
  __syncthreads();
  unsigned short* dst = pack + ((size_t)b*Hq + r)*Wq*128;
  for (int i = 0; i < 16; i++) {
    int gidx = i*192 + t;                // 3072 granules of 16B
    int c = gidx >> 4, sub = gidx & 15;
    int hl = sub >> 3, g8 = sub & 7;     // sub 0..7 = hi chs, 8..15 = lo chs
    unsigned short tmp[8];
#pragma unroll
    for (int j = 0; j < 8; j++) {
      int ch = g8*8 + j;
      unsigned int u = s[c*64 + (ch ^ (c & 31))];
      tmp[j] = hl ? (unsigned short)(u >> 16) : (unsigned short)(u & 0xffff);
    }
    uint4 v;
    v.x = (unsigned int)tmp[0] | ((unsigned int)tmp[1] << 16);
    v.y = (unsigned int)tmp[2] | ((unsigned int)tmp[3] << 16);
    v.z = (unsigned int)tmp[4] | ((unsigned int)tmp[5] << 16);
    v.w = (unsigned int)tmp[6] | ((unsigned int)tmp[7] << 16);
    *(uint4*)(dst + (size_t)gidx*8) = v;
  }
}

// ---------------------------------------------------------------------------
// 7x7 conv via MFMA (f16 hi/lo 3-pass) — unchanged from round 5
// ---------------------------------------------------------------------------
__global__ __launch_bounds__(192) void conv7_mfma_kernel(
    const unsigned short* __restrict__ xpack,
    const unsigned short* __restrict__ wpack,
    float* __restrict__ out)
{
  __shared__ __align__(16) unsigned short sA[9*54*64];
  int ct = blockIdx.x;
  int rt = blockIdx.y;
  int b  = blockIdx.z;
  int r0 = rt*3, c0 = ct*48;
  int t = threadIdx.x;
  int w = t >> 6;
  int l = t & 63;
  int l15 = l & 15, lg = l >> 4;

  f32x4 acc[3][4];
#pragma unroll
  for (int i = 0; i < 3; i++)
#pragma unroll
    for (int j = 0; j < 4; j++) acc[i][j] = (f32x4){0.f,0.f,0.f,0.f};

  for (int h = 0; h < 2; h++) {
    __syncthreads();
    for (int idx = t; idx < 9*54*8; idx += 192) {
      int g = idx & 7, pix = idx >> 3;
      int row = pix / 54, col = pix % 54;
      int gr = r0 - 3 + row, gc = c0 - 3 + col;
      uint4 v = {0u,0u,0u,0u};
      if (gr >= 0 && gr < Hq && gc >= 0 && gc < Wq)
        v = *(const uint4*)(xpack + (((size_t)b*Hq + gr)*Wq + gc)*128 + (h*8 + g)*8);
      ((uint4*)sA)[(row*54 + col)*8 + (g ^ (col & 7))] = v;
    }
    __syncthreads();
    const unsigned short* wb = wpack + (size_t)h*49*4096;
    for (int tap = 0; tap < 49; tap++) {
      int dy = tap / 7, dx = tap % 7;
      f16x8 bh[4], bl[4];
#pragma unroll
      for (int tb = 0; tb < 4; tb++) {
        bh[tb] = *(const f16x8*)(wb + (size_t)tap*4096 + (tb*16 + l15)*32 + lg*8);
        bl[tb] = *(const f16x8*)(wb + (size_t)tap*4096 + 2048 + (tb*16 + l15)*32 + lg*8);
      }
      int arow = w + dy;
      f16x8 ah[3], al[3];
#pragma unroll
      for (int ta = 0; ta < 3; ta++) {
        int col = ta*16 + l15 + dx;
        const uint4* base = (const uint4*)sA + (arow*54 + col)*8;
        ah[ta] = *(const f16x8*)(base + (lg ^ (col & 7)));
        al[ta] = *(const f16x8*)(base + ((lg + 4) ^ (col & 7)));
      }
#pragma unroll
      for (int ta = 0; ta < 3; ta++)
#pragma unroll
        for (int tb = 0; tb < 4; tb++) {
          acc[ta][tb] = __builtin_amdgcn_mfma_f32_16x16x32_f16(ah[ta], bh[tb], acc[ta][tb], 0, 0, 0);
          acc[ta][tb] = __builtin_amdgcn_mfma_f32_16x16x32_f16(ah[ta], bl[tb], acc[ta][tb], 0, 0, 0);
          acc[ta][tb] = __builtin_amdgcn_mfma_f32_16x16x32_f16(al[ta], bh[tb], acc[ta][tb], 0, 0, 0);
        }
    }
  }
#pragma unroll
  for (int tb = 0; tb < 4; tb++) {
    int oc = tb*16 + l15;
    float* dst = out + ((size_t)(b*64 + oc)*Hq + (r0 + w))*Wq + c0;
#pragma unroll
    for (int ta = 0; ta < 3; ta++) {
      f32x4 v = acc[ta][tb];
      *(float4*)(dst + ta*16 + lg*4) = make_float4(v[0], v[1], v[2], v[3]);
    }
  }
}

// ---------------------------------------------------------------------------
// Separable 7x7 avg pool
// ---------------------------------------------------------------------------
__global__ __launch_bounds__(256) void pool_row_kernel(const float* __restrict__ in, float* __restrict__ out)
{
  int idx = blockIdx.x*256 + threadIdx.x;
  int c = idx % Wq;
  int base = idx - c;
  float s = 0.f;
#pragma unroll
  for (int dc = -3; dc <= 3; dc++) {
    int cc = c + dc;
    if (cc >= 0 && cc < Wq) s += in[base + cc];
  }
  out[idx] = s;
}

__global__ __launch_bounds__(256) void pool_col_kernel(const float* __restrict__ in, float* __restrict__ out)
{
  int idx = blockIdx.x*256 + threadIdx.x;
  int c = idx % Wq;
  int r = (idx / Wq) % Hq;
  int plane = idx / HWq;
  float s = 0.f;
#pragma unroll
  for (int dr = -3; dr <= 3; dr++) {
    int rr = r + dr;
    if (rr >= 0 && rr < Hq) s += in[(size_t)plane*HWq + rr*Wq + c];
  }
  out[idx] = s * (1.f/49.f);
}

// ---------------------------------------------------------------------------
// Depthwise chain: uniform 19-tap, class-selected weights
// ---------------------------------------------------------------------------
__global__ __launch_bounds__(256) void dw_h_kernel(const float* __restrict__ x1,
                                                   const float* __restrict__ wEff,
                                                   const float* __restrict__ bEff,
                                                   const float* __restrict__ wB,
                                                   float* __restrict__ out)
{
  __shared__ float sW[19][20];
  int b = blockIdx.z, ch = blockIdx.y;
  int t = threadIdx.x;
  for (int i = t; i < 380; i += 256) {
    int row = i / 20, jj = i % 20;
    float v;
    if (row < 18) v = wB[((size_t)ch*18 + row)*20 + jj];
    else v = (jj < 19) ? wEff[ch*19 + jj] : bEff[ch];
    sW[row][jj] = v;
  }
  __syncthreads();
  int p = blockIdx.x*256 + t;
  int r = p / Wq, c = p % Wq;
  const float* src = x1 + (size_t)(b*Cq + ch)*HWq + r*Wq;
  int row = (c < 9) ? c : ((c >= Wq-9) ? (c - 174) : 18);
  float s = sW[row][19];
#pragma unroll
  for (int j = 0; j < 19; j++) {
    int idx = min(max(c + j - 9, 0), Wq-1);
    s += src[idx] * sW[row][j];
  }
  out[(size_t)(b*Cq + ch)*HWq + p] = s;
}

__global__ __launch_bounds__(256) void dw_v_kernel(const float* __restrict__ x1,
                                                   const float* __restrict__ wEff,
                                                   const float* __restrict__ bEff,
                                                   const float* __restrict__ wB,
                                                   float* __restrict__ out)
{
  __shared__ float sW[19][20];
  int b = blockIdx.z, ch = blockIdx.y;
  int t = threadIdx.x;
  for (int i = t; i < 380; i += 256) {
    int row = i / 20, jj = i % 20;
    float v;
    if (row < 18) v = wB[((size_t)ch*18 + row)*20 + jj];
    else v = (jj < 19) ? wEff[ch*19 + jj] : bEff[ch];
    sW[row][jj] = v;
  }
  __syncthreads();
  int p = blockIdx.x*256 + t;
  int r = p / Wq, c = p % Wq;
  const float* src = x1 + (size_t)(b*Cq + ch)*HWq + c;
  int row = (r < 9) ? r : ((r >= Hq-9) ? (r - 174) : 18);
  float s = sW[row][19];
#pragma unroll
  for (int j = 0; j < 19; j++) {
    int idx = min(max(r + j - 9, 0), Hq-1);
    s += src[idx*Wq] * sW[row][j];
  }
  out[(size_t)(b*Cq + ch)*HWq + p] = s;
}

// ---------------------------------------------------------------------------
// Offset conv + tanh + cum, reading fpack (NHWC f16 hi/lo)
// ---------------------------------------------------------------------------
__global__ __launch_bounds__(256) void off_cum_kernel(const unsigned short* __restrict__ fp,
                                                      const float* __restrict__ wOff,
                                                      const float* __restrict__ bOff,
                                                      float* __restrict__ cum)
{
  int b = blockIdx.y;
  int p = blockIdx.x*256 + threadIdx.x;
  int r = p / Wq, c = p % Wq;
  float tv[7];
#pragma unroll
  for (int m = 0; m < 7; m++) tv[m] = bOff[m];
  const unsigned short* fb = fp + (size_t)b*HWq*128;
  for (int tap = 0; tap < 9; tap++) {
    int dy = tap/3 - 1, dx = tap%3 - 1;
    int rr = r + dy, cc = c + dx;
    if (rr < 0 || rr >= Hq || cc < 0 || cc >= Wq) continue;
    const uint4* f0 = (const uint4*)(fb + ((size_t)rr*Wq + cc)*128);
    const float* wp = wOff + tap*512;
    for (int g = 0; g < 8; g++) {
      f16x8 hv = *(const f16x8*)(f0 + g);
      f16x8 lv = *(const f16x8*)(f0 + 8 + g);
#pragma unroll
      for (int e = 0; e < 8; e++) {
        float fv = (float)hv[e] + (float)lv[e];
        const float* wr = wp + (g*8 + e)*8;
#pragma unroll
        for (int m = 0; m < 7; m++) tv[m] += fv * wr[m];
      }
    }
  }
#pragma unroll
  for (int m = 0; m < 7; m++) tv[m] = tanhf(tv[m]);
  float c0 = tv[0], c1 = tv[1] + tv[2], c2 = tv[2], c3 = 0.f;
  float c4 = tv[4], c5 = tv[4] + tv[5], c6 = tv[6];
  size_t bb = (size_t)b*7*HWq + p;
  cum[bb + 0*HWq] = c0; cum[bb + 1*HWq] = c1; cum[bb + 2*HWq] = c2;
  cum[bb + 3*HWq] = c3; cum[bb + 4*HWq] = c4; cum[bb + 5*HWq] = c5;
  cum[bb + 6*HWq] = c6;
}

// ---------------------------------------------------------------------------
// Deformable sample + einsum via MFMA (f16 hi/lo 3-pass).
// Block = 128 px (2 waves, wave-private A-tile). MORPH selects geometry.
// ---------------------------------------------------------------------------
template<int MORPH>
__global__ __launch_bounds__(128) void einsum_mfma_kernel(
    const unsigned short* __restrict__ fp,   // fpack [px][hi64|lo64]
    const float* __restrict__ cum,
    const unsigned short* __restrict__ wtp,  // [tap][kc][hl][oc][32] f16
    const float* __restrict__ dsc_b,
    float* __restrict__ out)                 // NCHW f32
{
  __shared__ __align__(16) unsigned short sA[2*64*128];  // 32 KB
  int b = blockIdx.y;
  int t = threadIdx.x;
  int w = t >> 6, l = t & 63;
  int l15 = l & 15, lg = l >> 4;
  int p = blockIdx.x*128 + w*64 + l;
  int r = p / Wq, c = p % Wq;

  f32x4 acc[4][4];
#pragma unroll
  for (int i = 0; i < 4; i++)
#pragma unroll
    for (int j = 0; j < 4; j++) acc[i][j] = (f32x4){0.f,0.f,0.f,0.f};

  const unsigned short* fb = fp + (size_t)b*HWq*128;
  unsigned short* myrow = sA + (size_t)(w*64 + l)*128;

  for (int k = 0; k < 7; k++) {
    // ---- stage: this thread's pixel sample (64 ch, hi/lo f16) -------------
    bool oob;
    const uint4 *f0, *f1;
    float w0, w1;
    if (MORPH == 0) {
      int xi = c + k - 3;
      oob = (xi < 0 || xi >= Wq);
      if (!oob) {
        float y = (float)r + cum[((size_t)(b*7 + k))*HWq + p];
        float y0 = floorf(y);
        int y0q = (int)y0;
        int y0i = min(max(y0q, 0), Hq-1);
        int y1i = min(max(y0q + 1, 0), Hq-1);
        float y0f = fminf(fmaxf(y0, 0.f), (float)Hq);
        float y1f = fminf(fmaxf(y0 + 1.f, 0.f), (float)Hq);
        w0 = y1f - y; w1 = y - y0f;
        f0 = (const uint4*)(fb + ((size_t)y0i*Wq + xi)*128);
        f1 = (const uint4*)(fb + ((size_t)y1i*Wq + xi)*128);
      }
    } else {
      int yi = r + k - 3;
      oob = (yi < 0 || yi >= Hq);
      if (!oob) {
        float xf = (float)c + cum[((size_t)(b*7 + k))*HWq + p];
        float x0 = floorf(xf);
        int x0q = (int)x0;
        int x0i = min(max(x0q, 0), Wq-1);
        int x1i = min(max(x0q + 1, 0), Wq-1);
        float x0f = fminf(fmaxf(x0, 0.f), (float)Wq);
        float x1f = fminf(fmaxf(x0 + 1.f, 0.f), (float)Wq);
        w0 = x1f - xf; w1 = xf - x0f;
        f0 = (const uint4*)(fb + ((size_t)yi*Wq + x0i)*128);
        f1 = (const uint4*)(fb + ((size_t)yi*Wq + x1i)*128);
      }
    }
    if (oob) {
      uint4 z = {0u,0u,0u,0u};
#pragma unroll
      for (int j = 0; j < 16; j++) ((uint4*)myrow)[j] = z;
    } else {
#pragma unroll
      for (int g = 0; g < 8; g++) {
        f16x8 a0h = *(const f16x8*)(f0 + g);
        f16x8 a0l = *(const f16x8*)(f0 + 8 + g);
        f16x8 a1h = *(const f16x8*)(f1 + g);
        f16x8 a1l = *(const f16x8*)(f1 + 8 + g);
        f16x8 sh, sl;
#pragma unroll
        for (int e = 0; e < 8; e++) {
          float v = w0*((float)a0h[e] + (float)a0l[e]) + w1*((float)a1h[e] + (float)a1l[e]);
          _Float16 vh = (_Float16)v;
          sh[e] = vh;
          sl[e] = (_Float16)(v - (float)vh);
        }
        *(f16x8*)(myrow + (size_t)(g ^ l15)*8)       = sh;
        *(f16x8*)(myrow + (size_t)((8 + g) ^ l15)*8) = sl;
      }
    }
    __syncthreads();
    // ---- MFMA over 2 K-chunks of 32 ch, 3 precision passes ----------------
#pragma unroll
    for (int kc = 0; kc < 2; kc++) {
      const unsigned short* wbase = wtp + (size_t)((k*2 + kc)*2)*2048;
      f16x8 bh[4], bl[4];
#pragma unroll
      for (int tb = 0; tb < 4; tb++) {
        bh[tb] = *(const f16x8*)(wbase + (tb*16 + l15)*32 + lg*8);
        bl[tb] = *(const f16x8*)(wbase + 2048 + (tb*16 + l15)*32 + lg*8);
      }
      f16x8 ah[4], al[4];
#pragma unroll
      for (int ta = 0; ta < 4; ta++) {
        const unsigned short* rbase = sA + (size_t)(w*64 + ta*16 + l15)*128;
        ah[ta] = *(const f16x8*)(rbase + (size_t)((kc*4 + lg) ^ l15)*8);
        al[ta] = *(const f16x8*)(rbase + (size_t)((8 + kc*4 + lg) ^ l15)*8);
      }
#pragma unroll
      for (int ta = 0; ta < 4; ta++)
#pragma unroll
        for (int tb = 0; tb < 4; tb++) {
          acc[ta][tb] = __builtin_amdgcn_mfma_f32_16x16x32_f16(ah[ta], bh[tb], acc[ta][tb], 0, 0, 0);
          acc[ta][tb] = __builtin_amdgcn_mfma_f32_16x16x32_f16(ah[ta], bl[tb], acc[ta][tb], 0, 0, 0);
          acc[ta][tb] = __builtin_amdgcn_mfma_f32_16x16x32_f16(al[ta], bh[tb], acc[ta][tb], 0, 0, 0);
        }
    }
    __syncthreads();
  }
  // ---- epilogue: add bias, write NCHW f32 ---------------------------------
  int pbase = blockIdx.x*128 + w*64;
#pragma unroll
  for (int tb = 0; tb < 4; tb++) {
    int oc = tb*16 + l15;
    float bias = dsc_b[oc];
    float* dst = out + (size_t)(b*64 + oc)*HWq + pbase;
#pragma unroll
    for (int ta = 0; ta < 4; ta++) {
      f32x4 v = acc[ta][tb];
      *(float4*)(dst + ta*16 + lg*4) = make_float4(v[0]+bias, v[1]+bias, v[2]+bias, v[3]+bias);
    }
  }
}

// ---------------------------------------------------------------------------
// GroupNorm stats + finalize + combine + final 1x1 + SiLU
// ---------------------------------------------------------------------------
__global__ __launch_bounds__(256) void gnstats_kernel(const float* __restrict__ h_ds,
                                                      const float* __restrict__ v_ds,
                                                      float* __restrict__ stats)
{
  int plane = blockIdx.x;
  int buf = plane >> 7;
  int rem = plane & 127;
  const float* src = (buf ? v_ds : h_ds) + (size_t)rem*HWq;
  float s = 0.f, s2 = 0.f;
  for (int i = threadIdx.x; i < HWq; i += 256) {
    float v = src[i];
    s += v; s2 += v*v;
  }
  __shared__ float red[2][4];
  for (int off = 32; off; off >>= 1) {
    s  += __shfl_down(s, off);
    s2 += __shfl_down(s2, off);
  }
  if ((threadIdx.x & 63) == 0) { red[0][threadIdx.x >> 6] = s; red[1][threadIdx.x >> 6] = s2; }
  __syncthreads();
  if (threadIdx.x == 0) {
    s  = red[0][0] + red[0][1] + red[0][2] + red[0][3];
    s2 = red[1][0] + red[1][1] + red[1][2] + red[1][3];
    stats[plane*2 + 0] = s;
    stats[plane*2 + 1] = s2;
  }
}

__global__ __launch_bounds__(256) void gnfinal_kernel(const float* __restrict__ stats,
                                                      const float* __restrict__ h_gn_g, const float* __restrict__ h_gn_b,
                                                      const float* __restrict__ v_gn_g, const float* __restrict__ v_gn_b,
                                                      float* __restrict__ gnAB)
{
  int t = threadIdx.x;
  int buf = t >> 7, ch = t & 63;
  int base = t & ~3;
  float sum = 0.f, ss = 0.f;
#pragma unroll
  for (int q = 0; q < 4; q++) { sum += stats[(base+q)*2]; ss += stats[(base+q)*2 + 1]; }
  const float n = 4.f * HWq;
  float mean = sum / n;
  float var = ss / n - mean*mean;
  float gg = (buf ? v_gn_g : h_gn_g)[ch];
  float bb = (buf ? v_gn_b : h_gn_b)[ch];
  float A = gg / sqrtf(var + 1e-5f);
  gnAB[t*2 + 0] = A;
  gnAB[t*2 + 1] = bb - mean*A;
}

__global__ __launch_bounds__(256) void combine_kernel(const float* __restrict__ h_ds,
                                                      const float* __restrict__ v_ds,
                                                      const float* __restrict__ x1,
                                                      const float* __restrict__ gnAB,
                                                      float* __restrict__ comb)
{
  size_t idx = (size_t)blockIdx.x*256 + threadIdx.x;
  int plane = (int)(idx / HWq);
  int ih = plane*2;
  int iv = (128 + plane)*2;
  float hv = h_ds[idx]*gnAB[ih] + gnAB[ih+1]; hv = fmaxf(hv, 0.f);
  float vv = v_ds[idx]*gnAB[iv] + gnAB[iv+1]; vv = fmaxf(vv, 0.f);
  comb[idx] = hv + vv + x1[idx];
}

__global__ __launch_bounds__(256) void final_kernel(const float* __restrict__ comb,
                                                    const float* __restrict__ lwT,
                                                    const float* __restrict__ lbO,
                                                    float* __restrict__ out)
{
  int b = blockIdx.y;
  int p = blockIdx.x*256 + threadIdx.x;
  const float* cb = comb + (size_t)b*Cq*HWq + p;
  float acc[64];
#pragma unroll
  for (int o = 0; o < 64; o++) acc[o] = 0.f;
  for (int i = 0; i < 64; i++) {
    float cv = cb[(size_t)i*HWq];
    const float* wr = lwT + i*64;
#pragma unroll
    for (int o = 0; o < 64; o++) acc[o] += cv * wr[o];
  }
  float* dst = out + (size_t)b*Cq*HWq + p;
#pragma unroll
  for (int o = 0; o < 64; o++) {
    float yv = acc[o] + lbO[o];
    dst[(size_t)o*HWq] = yv / (1.f + expf(-yv));
  }
}

// ---------------------------------------------------------------------------
extern "C" void kernel_launch(void* const* d_in, const int* in_sizes, int n_in,
                              void* d_out, int out_size, void* d_ws, size_t ws_size,
                              hipStream_t stream)
{
  const float* x       = (const float*)d_in[0];
  const float* w_first = (const float*)d_in[1];
  float* ws = (float*)d_ws;

  float* bufA = ws;            // conv7 out -> hfeat -> h-einsum-out
  float* bufB = ws + Nq;       // rowsum -> vfeat -> v-einsum-out
  float* x1   = ws + 2*Nq;
  float* h_ds = ws + 3*Nq;     // xpack -> fpackH -> comb
  float* v_ds = ws + 4*Nq;     // fpackV
  size_t off = 5*Nq;
  float* hcum  = ws + off; off += (size_t)Bq*7*HWq;
  float* vcum  = ws + off; off += (size_t)Bq*7*HWq;
  float* wEffH = ws + off; off += 64*19;
  float* bEffH = ws + off; off += 64;
  float* wEffV = ws + off; off += 64*19;
  float* bEffV = ws + off; off += 64;
  float* wtH   = ws + off; off += 64*64*7;   // holds wtpH f16 pack
  float* wtV   = ws + off; off += 64*64*7;   // holds wtpV f16 pack
  float* wOffH = ws + off; off += 9*64*8;
  float* bOffH = ws + off; off += 8;
  float* wOffV = ws + off; off += 9*64*8;
  float* bOffV = ws + off; off += 8;
  float* lwT   = ws + off; off += 64*64;
  float* lbO   = ws + off; off += 64;
  float* stats = ws + off; off += 512;
  float* gnAB  = ws + off; off += 512;
  float* wB    = ws + off; off += 2*64*18*20;
  unsigned short* wpack = (unsigned short*)(ws + off); off += 2*49*2*64*32/2 + 16;
  unsigned short* xpack  = (unsigned short*)h_ds;
  unsigned short* fpackH = (unsigned short*)h_ds;
  unsigned short* fpackV = (unsigned short*)v_ds;
  unsigned short* wtpH = (unsigned short*)wtH;
  unsigned short* wtpV = (unsigned short*)wtV;

  prep_small_kernel<<<dim3(1), dim3(256), 0, stream>>>(
      (const float*)d_in[2],  (const float*)d_in[3],  (const float*)d_in[4],  (const float*)d_in[5],
      (const float*)d_in[6],  (const float*)d_in[7],
      (const float*)d_in[8],  (const float*)d_in[9],  (const float*)d_in[10], (const float*)d_in[11],
      (const float*)d_in[12], (const float*)d_in[13],
      (const float*)d_in[14], (const float*)d_in[15], (const float*)d_in[16], (const float*)d_in[17],
      (const float*)d_in[18], (const float*)d_in[19],
      (const float*)d_in[24], (const float*)d_in[25], (const float*)d_in[26], (const float*)d_in[27],
      (const float*)d_in[28], (const float*)d_in[29],
      (const float*)d_in[34], (const float*)d_in[35], (const float*)d_in[36], (const float*)d_in[37],
      (const float*)d_in[38],
      wEffH, bEffH, wEffV, bEffV, wOffH, bOffH, wOffV, bOffV, lwT, lbO);

  prep_border_kernel<<<dim3(9), dim3(256), 0, stream>>>(
      (const float*)d_in[2],  (const float*)d_in[3],  (const float*)d_in[4],  (const float*)d_in[5],
      (const float*)d_in[6],  (const float*)d_in[7],
      (const float*)d_in[8],  (const float*)d_in[9],  (const float*)d_in[10], (const float*)d_in[11],
      (const float*)d_in[12], (const float*)d_in[13], wB);

  prep_big_kernel<<<dim3(64), dim3(256), 0, stream>>>(
      w_first, (const float*)d_in[20], (const float*)d_in[30], wtpH, wtpV, wpack);

  tof16_pack_kernel<<<dim3(Hq, Bq), dim3(192), 0, stream>>>(x, xpack);
  conv7_mfma_kernel<<<dim3(4, 64, 2), dim3(192), 0, stream>>>(xpack, wpack, bufA);

  pool_row_kernel<<<dim3(18432), dim3(256), 0, stream>>>(bufA, bufB);
  pool_col_kernel<<<dim3(18432), dim3(256), 0, stream>>>(bufB, x1);

  dw_h_kernel<<<dim3(144, 64, 2), dim3(256), 0, stream>>>(x1, wEffH, bEffH, wB, bufA);
  dw_v_kernel<<<dim3(144, 64, 2), dim3(256), 0, stream>>>(x1, wEffV, bEffV, wB + 64*18*20, bufB);

  fpack_kernel<<<dim3(Hq, Bq), dim3(192), 0, stream>>>(bufA, fpackH);
  fpack_kernel<<<dim3(Hq, Bq), dim3(192), 0, stream>>>(bufB, fpackV);

  off_cum_kernel<<<dim3(144, 2), dim3(256), 0, stream>>>(fpackH, wOffH, bOffH, hcum);
  off_cum_kernel<<<dim3(144, 2), dim3(256), 0, stream>>>(fpackV, wOffV, bOffV, vcum);

  einsum_mfma_kernel<0><<<dim3(288, 2), dim3(128), 0, stream>>>(fpackH, hcum, wtpH, (const float*)d_in[21], bufA);
  einsum_mfma_kernel<1><<<dim3(288, 2), dim3(128), 0, stream>>>(fpackV, vcum, wtpV, (const float*)d_in[31], bufB);

  gnstats_kernel<<<dim3(256), dim3(256), 0, stream>>>(bufA, bufB, stats);
  gnfinal_kernel<<<dim3(1), dim3(256), 0, stream>>>(stats,
      (const float*)d_in[22], (const float*)d_in[23],
      (const float*)d_in[32], (const float*)d_in[33], gnAB);

  combine_kernel<<<dim3(18432), dim3(256), 0, stream>>>(bufA, bufB, x1, gnAB, h_ds);
  final_kernel<<<dim3(144, 2), dim3(256), 0, stream>>>(h_ds, lwT, lbO, (float*)d_out);
}

// Round 8
// 597.058 us; speedup vs baseline: 3.1146x; 1.2746x over previous
//
#include <hip/hip_runtime.h>
#include <hip/hip_bf16.h>
#include <hip/hip_fp16.h>
#include <math.h>

#define Bq 2
#define Cq 64
#define Hq 192
#define Wq 192
#define HWq (Hq*Wq)            // 36864
#define Nq ((size_t)Bq*Cq*HWq) // 4718592

typedef __attribute__((ext_vector_type(8))) _Float16 f16x8;
typedef __attribute__((ext_vector_type(4))) float f32x4;

__device__ inline unsigned short h2us(__half h) {
  union { __half h; unsigned short u; } v; v.h = h; return v.u;
}

// ---------------------------------------------------------------------------
// Small prep (1 block)
// ---------------------------------------------------------------------------
__global__ __launch_bounds__(256) void prep_small_kernel(
    const float* hc1_w, const float* hc1_b, const float* hc2_w, const float* hc2_b,
    const float* hc3_w, const float* hc3_b,
    const float* vc1_w, const float* vc1_b, const float* vc2_w, const float* vc2_b,
    const float* vc3_w, const float* vc3_b,
    const float* h_off_w, const float* h_off_b, const float* h_bn_g, const float* h_bn_b,
    const float* h_bn_m, const float* h_bn_v,
    const float* v_off_w, const float* v_off_b, const float* v_bn_g, const float* v_bn_b,
    const float* v_bn_m, const float* v_bn_v,
    const float* last_w, const float* last_g, const float* last_b, const float* last_m,
    const float* last_v,
    float* wEffH, float* bEffH, float* wEffV, float* bEffV,
    float* wOffH, float* bOffH, float* wOffV, float* bOffV,
    float* lwT, float* lbO)
{
  int t = threadIdx.x;
  if (t < 128) {
    int ch = t & 63;
    bool ish = t < 64;
    const float* w1 = (ish ? hc1_w : vc1_w) + ch*9;
    const float* w2 = (ish ? hc2_w : vc2_w) + ch*7;
    const float* w3 = (ish ? hc3_w : vc3_w) + ch*5;
    float t15[15];
    for (int s = 0; s < 15; s++) {
      float a = 0.f;
      for (int j = 0; j < 9; j++) { int k2 = s - j; if (k2 >= 0 && k2 < 7) a += w1[j]*w2[k2]; }
      t15[s] = a;
    }
    float* we = (ish ? wEffH : wEffV) + ch*19;
    for (int s = 0; s < 19; s++) {
      float a = 0.f;
      for (int j = 0; j < 15; j++) { int k3 = s - j; if (k3 >= 0 && k3 < 5) a += t15[j]*w3[k3]; }
      we[s] = a;
    }
    float S2 = 0.f, S3 = 0.f;
    for (int j = 0; j < 7; j++) S2 += w2[j];
    for (int j = 0; j < 5; j++) S3 += w3[j];
    float b1 = (ish ? hc1_b : vc1_b)[ch];
    float b2 = (ish ? hc2_b : vc2_b)[ch];
    float b3 = (ish ? hc3_b : vc3_b)[ch];
    (ish ? bEffH : bEffV)[ch] = b1*S2*S3 + b2*S3 + b3;
  }
  for (int idx = t; idx < 9*64*7; idx += 256) {
    int tap = idx / 448; int rem = idx % 448; int i = rem / 7; int m = rem % 7;
    float invh = h_bn_g[m] / sqrtf(h_bn_v[m] + 1e-5f);
    wOffH[(tap*64 + i)*8 + m] = h_off_w[(m*64 + i)*9 + tap] * invh;
    float invv = v_bn_g[7+m] / sqrtf(v_bn_v[7+m] + 1e-5f);
    wOffV[(tap*64 + i)*8 + m] = v_off_w[((7+m)*64 + i)*9 + tap] * invv;
  }
  if (t < 7) {
    float invh = h_bn_g[t] / sqrtf(h_bn_v[t] + 1e-5f);
    bOffH[t] = h_off_b[t]*invh + h_bn_b[t] - h_bn_m[t]*invh;
    float invv = v_bn_g[7+t] / sqrtf(v_bn_v[7+t] + 1e-5f);
    bOffV[t] = v_off_b[7+t]*invv + v_bn_b[7+t] - v_bn_m[7+t]*invv;
  }
  for (int idx = t; idx < 4096; idx += 256) {
    int o = idx % 64; int i = idx / 64;
    float inv = last_g[o] / sqrtf(last_v[o] + 1e-3f);
    lwT[i*64 + o] = last_w[o*64 + i] * inv;
  }
  if (t < 64) {
    float inv = last_g[t] / sqrtf(last_v[t] + 1e-3f);
    lbO[t] = last_b[t] - last_m[t]*inv;
  }
}

// ---------------------------------------------------------------------------
// Border prep (impulse-response composed clipped 19-tap weights)
// ---------------------------------------------------------------------------
__global__ __launch_bounds__(256) void prep_border_kernel(
    const float* hc1_w, const float* hc1_b, const float* hc2_w, const float* hc2_b,
    const float* hc3_w, const float* hc3_b,
    const float* vc1_w, const float* vc1_b, const float* vc2_w, const float* vc2_b,
    const float* vc3_w, const float* vc3_b,
    float* wB)
{
  int tid = blockIdx.x*256 + threadIdx.x;
  if (tid >= 2*64*18) return;
  int cls = tid % 18;
  int ch  = (tid / 18) % 64;
  int br  = tid / (18*64);
  int c = (cls < 9) ? cls : cls + 174;
  const float* w1 = (br==0 ? hc1_w : vc1_w) + ch*9;
  const float* w2 = (br==0 ? hc2_w : vc2_w) + ch*7;
  const float* w3 = (br==0 ? hc3_w : vc3_w) + ch*5;
  float b1 = (br==0 ? hc1_b : vc1_b)[ch];
  float b2 = (br==0 ? hc2_b : vc2_b)[ch];
  float b3 = (br==0 ? hc3_b : vc3_b)[ch];
  float* dst = wB + ((size_t)(br*64 + ch)*18 + cls)*20;
  for (int cse = 0; cse < 20; cse++) {
    bool basis = (cse < 19);
    int fd = c + cse - 9;
    float B1 = basis ? 0.f : b1, B2 = basis ? 0.f : b2, B3 = basis ? 0.f : b3;
    float o3 = B3;
    for (int m = 0; m < 5; m++) {
      int d = c + m - 2;
      if (d < 0 || d >= Wq) continue;
      float o2 = B2;
      for (int k = 0; k < 7; k++) {
        int e = d + k - 3;
        if (e < 0 || e >= Wq) continue;
        float o1 = B1;
        if (basis) {
          int tp = fd - e + 4;
          if (tp >= 0 && tp < 9 && fd >= 0 && fd < Wq) o1 += w1[tp];
        }
        o2 += o1 * w2[k];
      }
      o3 += o2 * w3[m];
    }
    dst[cse] = o3;
  }
}

// ---------------------------------------------------------------------------
// Big prep: dsc weights -> f16 hi/lo MFMA pack [tap][kc][hl][oc][32]
//           + w_first f16 hi/lo pack for conv7.
// ---------------------------------------------------------------------------
__global__ __launch_bounds__(256) void prep_big_kernel(
    const float* __restrict__ w_first,
    const float* __restrict__ h_dsc_w, const float* __restrict__ v_dsc_w,
    unsigned short* __restrict__ wtpH, unsigned short* __restrict__ wtpV,
    unsigned short* __restrict__ wpack)
{
  int tid = blockIdx.x*256 + threadIdx.x;
  int nthr = gridDim.x*256;
  for (int idx = tid; idx < 7*2*2*64*32; idx += nthr) {
    int ch32 = idx & 31;
    int oc   = (idx >> 5) & 63;
    int hl   = (idx >> 11) & 1;
    int kc   = (idx >> 12) & 1;
    int tap  = idx >> 13;
    int i = kc*32 + ch32;
    float vh = h_dsc_w[oc*448 + i*7 + tap];
    float vv = v_dsc_w[oc*448 + i*7 + tap];
    _Float16 hh = (_Float16)vh;
    _Float16 hv = (_Float16)vv;
    unsigned short uh, uv;
    if (!hl) { uh = *(unsigned short*)&hh; uv = *(unsigned short*)&hv; }
    else {
      _Float16 lh = (_Float16)(vh - (float)hh);
      _Float16 lv = (_Float16)(vv - (float)hv);
      uh = *(unsigned short*)&lh; uv = *(unsigned short*)&lv;
    }
    wtpH[idx] = uh; wtpV[idx] = uv;
  }
  for (int e = tid; e < 2*49*2*64*32; e += nthr) {
    int ch  = e & 31;
    int oc  = (e >> 5) & 63;
    int hl  = (e >> 11) & 1;
    int rest = e >> 12;
    int tap = rest % 49;
    int h   = rest / 49;
    float wv = w_first[((size_t)oc*64 + h*32 + ch)*49 + tap];
    __half hh = __float2half(wv);
    unsigned short us;
    if (!hl) us = h2us(hh);
    else { float rr = wv - __half2float(hh); us = h2us(__float2half(rr)); }
    wpack[e] = us;
  }
}

// ---------------------------------------------------------------------------
// x (NCHW f32) -> xpack (conv7 layout): per pixel [h(2)][hl(2)][g8(4)] x 8 ch
// ---------------------------------------------------------------------------
__global__ __launch_bounds__(192) void tof16_pack_kernel(const float* __restrict__ x,
                                                         unsigned short* __restrict__ xpack)
{
  __shared__ unsigned int s[192*64];
  int r = blockIdx.x, b = blockIdx.y;
  int t = threadIdx.x;
  for (int ch = 0; ch < 64; ch++) {
    float v = x[((size_t)(b*64+ch)*Hq + r)*Wq + t];
    __half hh = __float2half(v);
    float rr = v - __half2float(hh);
    __half hl = __float2half(rr);
    unsigned int pk = (unsigned int)h2us(hh) | ((unsigned int)h2us(hl) << 16);
    s[t*64 + (ch ^ (t & 31))] = pk;
  }
  __syncthreads();
  unsigned short* dst = xpack + ((size_t)b*Hq + r)*Wq*128;
  for (int i = 0; i < 16; i++) {
    int gidx = i*192 + t;
    int c = gidx >> 4, sub = gidx & 15;
    int h = sub >> 3, hl = (sub >> 2) & 1, g8 = sub & 3;
    unsigned short tmp[8];
#pragma unroll
    for (int j = 0; j < 8; j++) {
      int ch = h*32 + g8*8 + j;
      unsigned int u = s[c*64 + (ch ^ (c & 31))];
      tmp[j] = hl ? (unsigned short)(u >> 16) : (unsigned short)(u & 0xffff);
    }
    uint4 v;
    v.x = (unsigned int)tmp[0] | ((unsigned int)tmp[1] << 16);
    v.y = (unsigned int)tmp[2] | ((unsigned int)tmp[3] << 16);
    v.z = (unsigned int)tmp[4] | ((unsigned int)tmp[5] << 16);
    v.w = (unsigned int)tmp[6] | ((unsigned int)tmp[7] << 16);
    *(uint4*)(dst + (size_t)gidx*8) = v;
  }
}

// ---------------------------------------------------------------------------
// feat (NCHW f32) -> fpack PLANE-MAJOR: [b][sub(16)][px][8ch] f16.
// sub 0..7 = hi granules (ch 8g..8g+7), sub 8..15 = lo granules.
// Writes fully coalesced per sub-plane.
// ---------------------------------------------------------------------------
__global__ __launch_bounds__(192) void fpack_kernel(const float* __restrict__ in,
                                                    unsigned short* __restrict__ pack)
{
  __shared__ unsigned int s[192*64];
  int r = blockIdx.x, b = blockIdx.y;
  int t = threadIdx.x;
  for (int ch = 0; ch < 64; ch++) {
    float v = in[((size_t)(b*64+ch)*Hq + r)*Wq + t];
    __half hh = __float2half(v);
    float rr = v - __half2float(hh);
    __half hl = __float2half(rr);
    unsigned int pk = (unsigned int)h2us(hh) | ((unsigned int)h2us(hl) << 16);
    s[t*64 + (ch ^ (t & 31))] = pk;
  }
  __syncthreads();
#pragma unroll
  for (int sub = 0; sub < 16; sub++) {
    int hl = sub >> 3, g8 = sub & 7;
    unsigned short tmp[8];
#pragma unroll
    for (int j = 0; j < 8; j++) {
      int ch = g8*8 + j;
      unsigned int u = s[t*64 + (ch ^ (t & 31))];
      tmp[j] = hl ? (unsigned short)(u >> 16) : (unsigned short)(u & 0xffff);
    }
    uint4 v;
    v.x = (unsigned int)tmp[0] | ((unsigned int)tmp[1] << 16);
    v.y = (unsigned int)tmp[2] | ((unsigned int)tmp[3] << 16);
    v.z = (unsigned int)tmp[4] | ((unsigned int)tmp[5] << 16);
    v.w = (unsigned int)tmp[6] | ((unsigned int)tmp[7] << 16);
    *(uint4*)(pack + (((size_t)b*16 + sub)*HWq + r*Wq + t)*8) = v;
  }
}

// ---------------------------------------------------------------------------
// 7x7 conv via MFMA (f16 hi/lo 3-pass)
// ---------------------------------------------------------------------------
__global__ __launch_bounds__(192) void conv7_mfma_kernel(
    const unsigned short* __restrict__ xpack,
    const unsigned short* __restrict__ wpack,
    float* __restrict__ out)
{
  __shared__ __align__(16) unsigned short sA[9*54*64];
  int ct = blockIdx.x;
  int rt = blockIdx.y;
  int b  = blockIdx.z;
  int r0 = rt*3, c0 = ct*48;
  int t = threadIdx.x;
  int w = t >> 6;
  int l = t & 63;
  int l15 = l & 15, lg = l >> 4;

  f32x4 acc[3][4];
#pragma unroll
  for (int i = 0; i < 3; i++)
#pragma unroll
    for (int j = 0; j < 4; j++) acc[i][j] = (f32x4){0.f,0.f,0.f,0.f};

  for (int h = 0; h < 2; h++) {
    __syncthreads();
    for (int idx = t; idx < 9*54*8; idx += 192) {
      int g = idx & 7, pix = idx >> 3;
      int row = pix / 54, col = pix % 54;
      int gr = r0 - 3 + row, gc = c0 - 3 + col;
      uint4 v = {0u,0u,0u,0u};
      if (gr >= 0 && gr < Hq && gc >= 0 && gc < Wq)
        v = *(const uint4*)(xpack + (((size_t)b*Hq + gr)*Wq + gc)*128 + (h*8 + g)*8);
      ((uint4*)sA)[(row*54 + col)*8 + (g ^ (col & 7))] = v;
    }
    __syncthreads();
    const unsigned short* wb = wpack + (size_t)h*49*4096;
    for (int tap = 0; tap < 49; tap++) {
      int dy = tap / 7, dx = tap % 7;
      f16x8 bh[4], bl[4];
#pragma unroll
      for (int tb = 0; tb < 4; tb++) {
        bh[tb] = *(const f16x8*)(wb + (size_t)tap*4096 + (tb*16 + l15)*32 + lg*8);
        bl[tb] = *(const f16x8*)(wb + (size_t)tap*4096 + 2048 + (tb*16 + l15)*32 + lg*8);
      }
      int arow = w + dy;
      f16x8 ah[3], al[3];
#pragma unroll
      for (int ta = 0; ta < 3; ta++) {
        int col = ta*16 + l15 + dx;
        const uint4* base = (const uint4*)sA + (arow*54 + col)*8;
        ah[ta] = *(const f16x8*)(base + (lg ^ (col & 7)));
        al[ta] = *(const f16x8*)(base + ((lg + 4) ^ (col & 7)));
      }
#pragma unroll
      for (int ta = 0; ta < 3; ta++)
#pragma unroll
        for (int tb = 0; tb < 4; tb++) {
          acc[ta][tb] = __builtin_amdgcn_mfma_f32_16x16x32_f16(ah[ta], bh[tb], acc[ta][tb], 0, 0, 0);
          acc[ta][tb] = __builtin_amdgcn_mfma_f32_16x16x32_f16(ah[ta], bl[tb], acc[ta][tb], 0, 0, 0);
          acc[ta][tb] = __builtin_amdgcn_mfma_f32_16x16x32_f16(al[ta], bh[tb], acc[ta][tb], 0, 0, 0);
        }
    }
  }
#pragma unroll
  for (int tb = 0; tb < 4; tb++) {
    int oc = tb*16 + l15;
    float* dst = out + ((size_t)(b*64 + oc)*Hq + (r0 + w))*Wq + c0;
#pragma unroll
    for (int ta = 0; ta < 3; ta++) {
      f32x4 v = acc[ta][tb];
      *(float4*)(dst + ta*16 + lg*4) = make_float4(v[0], v[1], v[2], v[3]);
    }
  }
}

// ---------------------------------------------------------------------------
// Separable 7x7 avg pool
// ---------------------------------------------------------------------------
__global__ __launch_bounds__(256) void pool_row_kernel(const float* __restrict__ in, float* __restrict__ out)
{
  int idx = blockIdx.x*256 + threadIdx.x;
  int c = idx % Wq;
  int base = idx - c;
  float s = 0.f;
#pragma unroll
  for (int dc = -3; dc <= 3; dc++) {
    int cc = c + dc;
    if (cc >= 0 && cc < Wq) s += in[base + cc];
  }
  out[idx] = s;
}

__global__ __launch_bounds__(256) void pool_col_kernel(const float* __restrict__ in, float* __restrict__ out)
{
  int idx = blockIdx.x*256 + threadIdx.x;
  int c = idx % Wq;
  int r = (idx / Wq) % Hq;
  int plane = idx / HWq;
  float s = 0.f;
#pragma unroll
  for (int dr = -3; dr <= 3; dr++) {
    int rr = r + dr;
    if (rr >= 0 && rr < Hq) s += in[(size_t)plane*HWq + rr*Wq + c];
  }
  out[idx] = s * (1.f/49.f);
}

// ---------------------------------------------------------------------------
// Depthwise chain: uniform 19-tap, class-selected weights
// ---------------------------------------------------------------------------
__global__ __launch_bounds__(256) void dw_h_kernel(const float* __restrict__ x1,
                                                   const float* __restrict__ wEff,
                                                   const float* __restrict__ bEff,
                                                   const float* __restrict__ wB,
                                                   float* __restrict__ out)
{
  __shared__ float sW[19][20];
  int b = blockIdx.z, ch = blockIdx.y;
  int t = threadIdx.x;
  for (int i = t; i < 380; i += 256) {
    int row = i / 20, jj = i % 20;
    float v;
    if (row < 18) v = wB[((size_t)ch*18 + row)*20 + jj];
    else v = (jj < 19) ? wEff[ch*19 + jj] : bEff[ch];
    sW[row][jj] = v;
  }
  __syncthreads();
  int p = blockIdx.x*256 + t;
  int r = p / Wq, c = p % Wq;
  const float* src = x1 + (size_t)(b*Cq + ch)*HWq + r*Wq;
  int row = (c < 9) ? c : ((c >= Wq-9) ? (c - 174) : 18);
  float s = sW[row][19];
#pragma unroll
  for (int j = 0; j < 19; j++) {
    int idx = min(max(c + j - 9, 0), Wq-1);
    s += src[idx] * sW[row][j];
  }
  out[(size_t)(b*Cq + ch)*HWq + p] = s;
}

__global__ __launch_bounds__(256) void dw_v_kernel(const float* __restrict__ x1,
                                                   const float* __restrict__ wEff,
                                                   const float* __restrict__ bEff,
                                                   const float* __restrict__ wB,
                                                   float* __restrict__ out)
{
  __shared__ float sW[19][20];
  int b = blockIdx.z, ch = blockIdx.y;
  int t = threadIdx.x;
  for (int i = t; i < 380; i += 256) {
    int row = i / 20, jj = i % 20;
    float v;
    if (row < 18) v = wB[((size_t)ch*18 + row)*20 + jj];
    else v = (jj < 19) ? wEff[ch*19 + jj] : bEff[ch];
    sW[row][jj] = v;
  }
  __syncthreads();
  int p = blockIdx.x*256 + t;
  int r = p / Wq, c = p % Wq;
  const float* src = x1 + (size_t)(b*Cq + ch)*HWq + c;
  int row = (r < 9) ? r : ((r >= Hq-9) ? (r - 174) : 18);
  float s = sW[row][19];
#pragma unroll
  for (int j = 0; j < 19; j++) {
    int idx = min(max(r + j - 9, 0), Hq-1);
    s += src[idx*Wq] * sW[row][j];
  }
  out[(size_t)(b*Cq + ch)*HWq + p] = s;
}

// ---------------------------------------------------------------------------
// Offset conv + tanh + cum, reading plane-major fpack (coalesced)
// ---------------------------------------------------------------------------
__global__ __launch_bounds__(256) void off_cum_kernel(const unsigned short* __restrict__ fp,
                                                      const float* __restrict__ wOff,
                                                      const float* __restrict__ bOff,
                                                      float* __restrict__ cum)
{
  const size_t HW8 = (size_t)HWq*8;
  int b = blockIdx.y;
  int p = blockIdx.x*256 + threadIdx.x;
  int r = p / Wq, c = p % Wq;
  float tv[7];
#pragma unroll
  for (int m = 0; m < 7; m++) tv[m] = bOff[m];
  const unsigned short* fb = fp + (size_t)b*HWq*128;
  for (int tap = 0; tap < 9; tap++) {
    int dy = tap/3 - 1, dx = tap%3 - 1;
    int rr = r + dy, cc = c + dx;
    if (rr < 0 || rr >= Hq || cc < 0 || cc >= Wq) continue;
    const unsigned short* p0 = fb + ((size_t)rr*Wq + cc)*8;
    const float* wp = wOff + tap*512;
    for (int g = 0; g < 8; g++) {
      f16x8 hv = *(const f16x8*)(p0 + (size_t)g*HW8);
      f16x8 lv = *(const f16x8*)(p0 + (size_t)(8 + g)*HW8);
#pragma unroll
      for (int e = 0; e < 8; e++) {
        float fv = (float)hv[e] + (float)lv[e];
        const float* wr = wp + (g*8 + e)*8;
#pragma unroll
        for (int m = 0; m < 7; m++) tv[m] += fv * wr[m];
      }
    }
  }
#pragma unroll
  for (int m = 0; m < 7; m++) tv[m] = tanhf(tv[m]);
  float c0 = tv[0], c1 = tv[1] + tv[2], c2 = tv[2], c3 = 0.f;
  float c4 = tv[4], c5 = tv[4] + tv[5], c6 = tv[6];
  size_t bb = (size_t)b*7*HWq + p;
  cum[bb + 0*HWq] = c0; cum[bb + 1*HWq] = c1; cum[bb + 2*HWq] = c2;
  cum[bb + 3*HWq] = c3; cum[bb + 4*HWq] = c4; cum[bb + 5*HWq] = c5;
  cum[bb + 6*HWq] = c6;
}

// ---------------------------------------------------------------------------
// Deformable sample + einsum via MFMA (f16 hi/lo 3-pass).
// Plane-major fpack reads (fully coalesced) + XCD-banded block swizzle.
// Grid: 1D 576 = (288 px-blocks) x (2 batches).
// ---------------------------------------------------------------------------
template<int MORPH>
__global__ __launch_bounds__(128) void einsum_mfma_kernel(
    const unsigned short* __restrict__ fp,   // fpack [b][sub16][px][8]
    const float* __restrict__ cum,
    const unsigned short* __restrict__ wtp,  // [tap][kc][hl][oc][32] f16
    const float* __restrict__ dsc_b,
    float* __restrict__ out)                 // NCHW f32
{
  __shared__ __align__(16) unsigned short sA[2*64*128];  // 32 KB
  const size_t HW8 = (size_t)HWq*8;
  int bid = blockIdx.x;                   // 0..575
  int swz = (bid & 7)*72 + (bid >> 3);    // XCD-contiguous bands (576 = 8*72)
  int b   = swz / 288;
  int blk = swz % 288;
  int t = threadIdx.x;
  int w = t >> 6, l = t & 63;
  int l15 = l & 15, lg = l >> 4;
  int p = blk*128 + w*64 + l;
  int r = p / Wq, c = p % Wq;

  f32x4 acc[4][4];
#pragma unroll
  for (int i = 0; i < 4; i++)
#pragma unroll
    for (int j = 0; j < 4; j++) acc[i][j] = (f32x4){0.f,0.f,0.f,0.f};

  const unsigned short* fb = fp + (size_t)b*HWq*128;
  unsigned short* myrow = sA + (size_t)(w*64 + l)*128;

  for (int k = 0; k < 7; k++) {
    bool oob;
    const unsigned short *p0, *p1;
    float w0, w1;
    if (MORPH == 0) {
      int xi = c + k - 3;
      oob = (xi < 0 || xi >= Wq);
      if (!oob) {
        float y = (float)r + cum[((size_t)(b*7 + k))*HWq + p];
        float y0 = floorf(y);
        int y0q = (int)y0;
        int y0i = min(max(y0q, 0), Hq-1);
        int y1i = min(max(y0q + 1, 0), Hq-1);
        float y0f = fminf(fmaxf(y0, 0.f), (float)Hq);
        float y1f = fminf(fmaxf(y0 + 1.f, 0.f), (float)Hq);
        w0 = y1f - y; w1 = y - y0f;
        p0 = fb + ((size_t)y0i*Wq + xi)*8;
        p1 = fb + ((size_t)y1i*Wq + xi)*8;
      }
    } else {
      int yi = r + k - 3;
      oob = (yi < 0 || yi >= Hq);
      if (!oob) {
        float xf = (float)c + cum[((size_t)(b*7 + k))*HWq + p];
        float x0 = floorf(xf);
        int x0q = (int)x0;
        int x0i = min(max(x0q, 0), Wq-1);
        int x1i = min(max(x0q + 1, 0), Wq-1);
        float x0f = fminf(fmaxf(x0, 0.f), (float)Wq);
        float x1f = fminf(fmaxf(x0 + 1.f, 0.f), (float)Wq);
        w0 = x1f - xf; w1 = xf - x0f;
        p0 = fb + ((size_t)yi*Wq + x0i)*8;
        p1 = fb + ((size_t)yi*Wq + x1i)*8;
      }
    }
    if (oob) {
      uint4 z = {0u,0u,0u,0u};
#pragma unroll
      for (int j = 0; j < 16; j++) ((uint4*)myrow)[j] = z;
    } else {
#pragma unroll
      for (int g = 0; g < 8; g++) {
        f16x8 a0h = *(const f16x8*)(p0 + (size_t)g*HW8);
        f16x8 a0l = *(const f16x8*)(p0 + (size_t)(8 + g)*HW8);
        f16x8 a1h = *(const f16x8*)(p1 + (size_t)g*HW8);
        f16x8 a1l = *(const f16x8*)(p1 + (size_t)(8 + g)*HW8);
        f16x8 sh, sl;
#pragma unroll
        for (int e = 0; e < 8; e++) {
          float v = w0*((float)a0h[e] + (float)a0l[e]) + w1*((float)a1h[e] + (float)a1l[e]);
          _Float16 vh = (_Float16)v;
          sh[e] = vh;
          sl[e] = (_Float16)(v - (float)vh);
        }
        *(f16x8*)(myrow + (size_t)(g ^ l15)*8)       = sh;
        *(f16x8*)(myrow + (size_t)((8 + g) ^ l15)*8) = sl;
      }
    }
    __syncthreads();
#pragma unroll
    for (int kc = 0; kc < 2; kc++) {
      const unsigned short* wbase = wtp + (size_t)((k*2 + kc)*2)*2048;
      f16x8 bh[4], bl[4];
#pragma unroll
      for (int tb = 0; tb < 4; tb++) {
        bh[tb] = *(const f16x8*)(wbase + (tb*16 + l15)*32 + lg*8);
        bl[tb] = *(const f16x8*)(wbase + 2048 + (tb*16 + l15)*32 + lg*8);
      }
      f16x8 ah[4], al[4];
#pragma unroll
      for (int ta = 0; ta < 4; ta++) {
        const unsigned short* rbase = sA + (size_t)(w*64 + ta*16 + l15)*128;
        ah[ta] = *(const f16x8*)(rbase + (size_t)((kc*4 + lg) ^ l15)*8);
        al[ta] = *(const f16x8*)(rbase + (size_t)((8 + kc*4 + lg) ^ l15)*8);
      }
#pragma unroll
      for (int ta = 0; ta < 4; ta++)
#pragma unroll
        for (int tb = 0; tb < 4; tb++) {
          acc[ta][tb] = __builtin_amdgcn_mfma_f32_16x16x32_f16(ah[ta], bh[tb], acc[ta][tb], 0, 0, 0);
          acc[ta][tb] = __builtin_amdgcn_mfma_f32_16x16x32_f16(ah[ta], bl[tb], acc[ta][tb], 0, 0, 0);
          acc[ta][tb] = __builtin_amdgcn_mfma_f32_16x16x32_f16(al[ta], bh[tb], acc[ta][tb], 0, 0, 0);
        }
    }
    __syncthreads();
  }
  int pbase = blk*128 + w*64;
#pragma unroll
  for (int tb = 0; tb < 4; tb++) {
    int oc = tb*16 + l15;
    float bias = dsc_b[oc];
    float* dst = out + (size_t)(b*64 + oc)*HWq + pbase;
#pragma unroll
    for (int ta = 0; ta < 4; ta++) {
      f32x4 v = acc[ta][tb];
      *(float4*)(dst + ta*16 + lg*4) = make_float4(v[0]+bias, v[1]+bias, v[2]+bias, v[3]+bias);
    }
  }
}

// ---------------------------------------------------------------------------
// GroupNorm stats + finalize + combine + final 1x1 + SiLU
// ---------------------------------------------------------------------------
__global__ __launch_bounds__(256) void gnstats_kernel(const float* __restrict__ h_ds,
                                                      const float* __restrict__ v_ds,
                                                      float* __restrict__ stats)
{
  int plane = blockIdx.x;
  int buf = plane >> 7;
  int rem = plane & 127;
  const float* src = (buf ? v_ds : h_ds) + (size_t)rem*HWq;
  float s = 0.f, s2 = 0.f;
  for (int i = threadIdx.x; i < HWq; i += 256) {
    float v = src[i];
    s += v; s2 += v*v;
  }
  __shared__ float red[2][4];
  for (int off = 32; off; off >>= 1) {
    s  += __shfl_down(s, off);
    s2 += __shfl_down(s2, off);
  }
  if ((threadIdx.x & 63) == 0) { red[0][threadIdx.x >> 6] = s; red[1][threadIdx.x >> 6] = s2; }
  __syncthreads();
  if (threadIdx.x == 0) {
    s  = red[0][0] + red[0][1] + red[0][2] + red[0][3];
    s2 = red[1][0] + red[1][1] + red[1][2] + red[1][3];
    stats[plane*2 + 0] = s;
    stats[plane*2 + 1] = s2;
  }
}

__global__ __launch_bounds__(256) void gnfinal_kernel(const float* __restrict__ stats,
                                                      const float* __restrict__ h_gn_g, const float* __restrict__ h_gn_b,
                                                      const float* __restrict__ v_gn_g, const float* __restrict__ v_gn_b,
                                                      float* __restrict__ gnAB)
{
  int t = threadIdx.x;
  int buf = t >> 7, ch = t & 63;
  int base = t & ~3;
  float sum = 0.f, ss = 0.f;
#pragma unroll
  for (int q = 0; q < 4; q++) { sum += stats[(base+q)*2]; ss += stats[(base+q)*2 + 1]; }
  const float n = 4.f * HWq;
  float mean = sum / n;
  float var = ss / n - mean*mean;
  float gg = (buf ? v_gn_g : h_gn_g)[ch];
  float bb = (buf ? v_gn_b : h_gn_b)[ch];
  float A = gg / sqrtf(var + 1e-5f);
  gnAB[t*2 + 0] = A;
  gnAB[t*2 + 1] = bb - mean*A;
}

__global__ __launch_bounds__(256) void combine_kernel(const float* __restrict__ h_ds,
                                                      const float* __restrict__ v_ds,
                                                      const float* __restrict__ x1,
                                                      const float* __restrict__ gnAB,
                                                      float* __restrict__ comb)
{
  size_t idx = (size_t)blockIdx.x*256 + threadIdx.x;
  int plane = (int)(idx / HWq);
  int ih = plane*2;
  int iv = (128 + plane)*2;
  float hv = h_ds[idx]*gnAB[ih] + gnAB[ih+1]; hv = fmaxf(hv, 0.f);
  float vv = v_ds[idx]*gnAB[iv] + gnAB[iv+1]; vv = fmaxf(vv, 0.f);
  comb[idx] = hv + vv + x1[idx];
}

__global__ __launch_bounds__(256) void final_kernel(const float* __restrict__ comb,
                                                    const float* __restrict__ lwT,
                                                    const float* __restrict__ lbO,
                                                    float* __restrict__ out)
{
  int b = blockIdx.y;
  int p = blockIdx.x*256 + threadIdx.x;
  const float* cb = comb + (size_t)b*Cq*HWq + p;
  float acc[64];
#pragma unroll
  for (int o = 0; o < 64; o++) acc[o] = 0.f;
  for (int i = 0; i < 64; i++) {
    float cv = cb[(size_t)i*HWq];
    const float* wr = lwT + i*64;
#pragma unroll
    for (int o = 0; o < 64; o++) acc[o] += cv * wr[o];
  }
  float* dst = out + (size_t)b*Cq*HWq + p;
#pragma unroll
  for (int o = 0; o < 64; o++) {
    float yv = acc[o] + lbO[o];
    dst[(size_t)o*HWq] = yv / (1.f + expf(-yv));
  }
}

// ---------------------------------------------------------------------------
extern "C" void kernel_launch(void* const* d_in, const int* in_sizes, int n_in,
                              void* d_out, int out_size, void* d_ws, size_t ws_size,
                              hipStream_t stream)
{
  const float* x       = (const float*)d_in[0];
  const float* w_first = (const float*)d_in[1];
  float* ws = (float*)d_ws;

  float* bufA = ws;            // conv7 out -> hfeat -> h-einsum-out
  float* bufB = ws + Nq;       // rowsum -> vfeat -> v-einsum-out
  float* x1   = ws + 2*Nq;
  float* h_ds = ws + 3*Nq;     // xpack -> fpackH -> comb
  float* v_ds = ws + 4*Nq;     // fpackV
  size_t off = 5*Nq;
  float* hcum  = ws + off; off += (size_t)Bq*7*HWq;
  float* vcum  = ws + off; off += (size_t)Bq*7*HWq;
  float* wEffH = ws + off; off += 64*19;
  float* bEffH = ws + off; off += 64;
  float* wEffV = ws + off; off += 64*19;
  float* bEffV = ws + off; off += 64;
  float* wtH   = ws + off; off += 64*64*7;   // holds wtpH f16 pack
  float* wtV   = ws + off; off += 64*64*7;   // holds wtpV f16 pack
  float* wOffH = ws + off; off += 9*64*8;
  float* bOffH = ws + off; off += 8;
  float* wOffV = ws + off; off += 9*64*8;
  float* bOffV = ws + off; off += 8;
  float* lwT   = ws + off; off += 64*64;
  float* lbO   = ws + off; off += 64;
  float* stats = ws + off; off += 512;
  float* gnAB  = ws + off; off += 512;
  float* wB    = ws + off; off += 2*64*18*20;
  unsigned short* wpack = (unsigned short*)(ws + off); off += 2*49*2*64*32/2 + 16;
  unsigned short* xpack  = (unsigned short*)h_ds;
  unsigned short* fpackH = (unsigned short*)h_ds;
  unsigned short* fpackV = (unsigned short*)v_ds;
  unsigned short* wtpH = (unsigned short*)wtH;
  unsigned short* wtpV = (unsigned short*)wtV;

  prep_small_kernel<<<dim3(1), dim3(256), 0, stream>>>(
      (const float*)d_in[2],  (const float*)d_in[3],  (const float*)d_in[4],  (const float*)d_in[5],
      (const float*)d_in[6],  (const float*)d_in[7],
      (const float*)d_in[8],  (const float*)d_in[9],  (const float*)d_in[10], (const float*)d_in[11],
      (const float*)d_in[12], (const float*)d_in[13],
      (const float*)d_in[14], (const float*)d_in[15], (const float*)d_in[16], (const float*)d_in[17],
      (const float*)d_in[18], (const float*)d_in[19],
      (const float*)d_in[24], (const float*)d_in[25], (const float*)d_in[26], (const float*)d_in[27],
      (const float*)d_in[28], (const float*)d_in[29],
      (const float*)d_in[34], (const float*)d_in[35], (const float*)d_in[36], (const float*)d_in[37],
      (const float*)d_in[38],
      wEffH, bEffH, wEffV, bEffV, wOffH, bOffH, wOffV, bOffV, lwT, lbO);

  prep_border_kernel<<<dim3(9), dim3(256), 0, stream>>>(
      (const float*)d_in[2],  (const float*)d_in[3],  (const float*)d_in[4],  (const float*)d_in[5],
      (const float*)d_in[6],  (const float*)d_in[7],
      (const float*)d_in[8],  (const float*)d_in[9],  (const float*)d_in[10], (const float*)d_in[11],
      (const float*)d_in[12], (const float*)d_in[13], wB);

  prep_big_kernel<<<dim3(64), dim3(256), 0, stream>>>(
      w_first, (const float*)d_in[20], (const float*)d_in[30], wtpH, wtpV, wpack);

  tof16_pack_kernel<<<dim3(Hq, Bq), dim3(192), 0, stream>>>(x, xpack);
  conv7_mfma_kernel<<<dim3(4, 64, 2), dim3(192), 0, stream>>>(xpack, wpack, bufA);

  pool_row_kernel<<<dim3(18432), dim3(256), 0, stream>>>(bufA, bufB);
  pool_col_kernel<<<dim3(18432), dim3(256), 0, stream>>>(bufB, x1);

  dw_h_kernel<<<dim3(144, 64, 2), dim3(256), 0, stream>>>(x1, wEffH, bEffH, wB, bufA);
  dw_v_kernel<<<dim3(144, 64, 2), dim3(256), 0, stream>>>(x1, wEffV, bEffV, wB + 64*18*20, bufB);

  fpack_kernel<<<dim3(Hq, Bq), dim3(192), 0, stream>>>(bufA, fpackH);
  fpack_kernel<<<dim3(Hq, Bq), dim3(192), 0, stream>>>(bufB, fpackV);

  off_cum_kernel<<<dim3(144, 2), dim3(256), 0, stream>>>(fpackH, wOffH, bOffH, hcum);
  off_cum_kernel<<<dim3(144, 2), dim3(256), 0, stream>>>(fpackV, wOffV, bOffV, vcum);

  einsum_mfma_kernel<0><<<dim3(576), dim3(128), 0, stream>>>(fpackH, hcum, wtpH, (const float*)d_in[21], bufA);
  einsum_mfma_kernel<1><<<dim3(576), dim3(128), 0, stream>>>(fpackV, vcum, wtpV, (const float*)d_in[31], bufB);

  gnstats_kernel<<<dim3(256), dim3(256), 0, stream>>>(bufA, bufB, stats);
  gnfinal_kernel<<<dim3(1), dim3(256), 0, stream>>>(stats,
      (const float*)d_in[22], (const float*)d_in[23],
      (const float*)d_in[32], (const float*)d_in[33], gnAB);

  combine_kernel<<<dim3(18432), dim3(256), 0, stream>>>(bufA, bufB, x1, gnAB, h_ds);
  final_kernel<<<dim3(144, 2), dim3(256), 0, stream>>>(h_ds, lwT, lbO, (float*)d_out);
}